// Round 1
// baseline (2436.984 us; speedup 1.0000x reference)
//
#include <hip/hip_runtime.h>

#define NG 978
#define BATCH 1024
#define MR 2048            // 2*BATCH stacked rows (enc1 rows 0..1023, enc2 1024..2047)
#define KPAD 1024          // padded K stride for agg (zero-padded cols 978..1023)
#define NEDGES 20480000
#define NNODES (BATCH * NG)   // 1001472
#define N1 2048            // fc1 out
#define N2 100             // fc2 out

// ws layout in floats: [agg (MR*KPAD) | C2 (MR*N2) | xi (2*NNODES) | C1 (MR*N1)]
// agg+C2 contiguous -> single memset.
#define OFF_AGG 0
#define OFF_C2  (OFF_AGG + MR * KPAD)                 // 2,097,152
#define OFF_XI  (OFF_C2 + MR * N2)                    // +204,800
#define OFF_C1  (OFF_XI + 2 * NNODES)                 // +2,002,944
// total = 8,499,200 floats = ~34 MB

// ---------------- interleave x1,x2 -> xi (float2 per node) ----------------
__global__ __launch_bounds__(256) void k_interleave(const float* __restrict__ x1,
                                                    const float* __restrict__ x2,
                                                    float* __restrict__ xi) {
    int i = blockIdx.x * 256 + threadIdx.x;   // float4 group index
    if (i >= NNODES / 4) return;
    float4 a = reinterpret_cast<const float4*>(x1)[i];
    float4 b = reinterpret_cast<const float4*>(x2)[i];
    float4 lo = make_float4(a.x, b.x, a.y, b.y);
    float4 hi = make_float4(a.z, b.z, a.w, b.w);
    reinterpret_cast<float4*>(xi)[2 * i + 0] = lo;
    reinterpret_cast<float4*>(xi)[2 * i + 1] = hi;
}

// ---------------- edge gather/scatter (both encoders fused) ----------------
__global__ __launch_bounds__(256) void k_edges(const int* __restrict__ edges,
                                               const float* __restrict__ xi,
                                               float* __restrict__ agg) {
    int t = blockIdx.x * 256 + threadIdx.x;
    int e = t * 4;
    const int4 s4 = *reinterpret_cast<const int4*>(edges + e);
    const int4 d4 = *reinterpret_cast<const int4*>(edges + NEDGES + e);
    int ss[4] = {s4.x, s4.y, s4.z, s4.w};
    int dd[4] = {d4.x, d4.y, d4.z, d4.w};
#pragma unroll
    for (int j = 0; j < 4; ++j) {
        int s = ss[j];
        int d = dd[j];
        float2 xv = *reinterpret_cast<const float2*>(xi + 2 * (size_t)s);
        int row = d / NG;            // magic-mul div by const
        int col = d - row * NG;
        float* p = agg + (size_t)row * KPAD + col;
        atomicAdd(p, xv.x);                       // encoder 1 plane
        atomicAdd(p + (size_t)BATCH * KPAD, xv.y); // encoder 2 plane
    }
}

// ---------------- GEMM1: C1 = relu( relu(agg*gw+gb) @ W + bias ) ----------------
// M=2048, K=978 (A K-stride 1024, zero-padded), N=2048. 128x128 tile, BK=16, 8x8/thread.
__global__ __launch_bounds__(256) void k_gemm1(const float* __restrict__ agg,
                                               const float* __restrict__ W,    // (978,2048)
                                               const float* __restrict__ bias, // (2048)
                                               const float* __restrict__ gwp,
                                               const float* __restrict__ gbp,
                                               float* __restrict__ C1) {
    __shared__ float As[16][132];   // transposed A tile: As[k][m], pad->2-way banks
    __shared__ float Bs[16][132];   // B tile with swizzled cols: phys = c + ((c>>6)<<2)
    const int tid = threadIdx.x;
    const int bm = blockIdx.y * 128;
    const int bn = blockIdx.x * 128;
    const float gw = gwp[0], gb = gbp[0];
    const int rt = tid >> 4;   // 0..15 -> rows rt*8..+7
    const int ct = tid & 15;   // 0..15 -> cols ct*8..+7

    float acc[8][8] = {};

    for (int k0 = 0; k0 < NG; k0 += 16) {
        // stage A: 128 rows x 16 k = 512 float4, 2 per thread; affine+relu applied here
#pragma unroll
        for (int h = 0; h < 2; ++h) {
            int i = tid + h * 256;
            int r = i >> 2;
            int k4 = (i & 3) << 2;
            float4 v = *reinterpret_cast<const float4*>(agg + (size_t)(bm + r) * KPAD + k0 + k4);
            v.x = fmaxf(v.x * gw + gb, 0.f);
            v.y = fmaxf(v.y * gw + gb, 0.f);
            v.z = fmaxf(v.z * gw + gb, 0.f);
            v.w = fmaxf(v.w * gw + gb, 0.f);
            As[k4 + 0][r] = v.x;
            As[k4 + 1][r] = v.y;
            As[k4 + 2][r] = v.z;
            As[k4 + 3][r] = v.w;
        }
        // stage B: 16 rows x 128 cols = 512 float4, 2 per thread (rows >= 978 zeroed)
#pragma unroll
        for (int h = 0; h < 2; ++h) {
            int i = tid + h * 256;
            int row = i >> 5;
            int c4 = (i & 31) << 2;
            int gk = k0 + row;
            float4 v = make_float4(0.f, 0.f, 0.f, 0.f);
            if (gk < NG) v = *reinterpret_cast<const float4*>(W + (size_t)gk * N1 + bn + c4);
            int pc = c4 + ((c4 >> 6) << 2);
            *reinterpret_cast<float4*>(&Bs[row][pc]) = v;
        }
        __syncthreads();
#pragma unroll
        for (int kk = 0; kk < 16; ++kk) {
            float4 a0 = *reinterpret_cast<const float4*>(&As[kk][rt * 8]);
            float4 a1 = *reinterpret_cast<const float4*>(&As[kk][rt * 8 + 4]);
            int cb = ct * 8;
            int pc = cb + ((cb >> 6) << 2);
            float4 b0 = *reinterpret_cast<const float4*>(&Bs[kk][pc]);
            float4 b1 = *reinterpret_cast<const float4*>(&Bs[kk][pc + 4]);
            float a[8] = {a0.x, a0.y, a0.z, a0.w, a1.x, a1.y, a1.z, a1.w};
            float b[8] = {b0.x, b0.y, b0.z, b0.w, b1.x, b1.y, b1.z, b1.w};
#pragma unroll
            for (int i2 = 0; i2 < 8; ++i2)
#pragma unroll
                for (int j2 = 0; j2 < 8; ++j2)
                    acc[i2][j2] = fmaf(a[i2], b[j2], acc[i2][j2]);
        }
        __syncthreads();
    }
    // epilogue: bias + relu
    const int cbase = bn + ct * 8;
    float4 bb0 = *reinterpret_cast<const float4*>(&bias[cbase]);
    float4 bb1 = *reinterpret_cast<const float4*>(&bias[cbase + 4]);
    float bz[8] = {bb0.x, bb0.y, bb0.z, bb0.w, bb1.x, bb1.y, bb1.z, bb1.w};
#pragma unroll
    for (int i2 = 0; i2 < 8; ++i2) {
        int row = bm + rt * 8 + i2;
        float4 o0, o1;
        o0.x = fmaxf(acc[i2][0] + bz[0], 0.f);
        o0.y = fmaxf(acc[i2][1] + bz[1], 0.f);
        o0.z = fmaxf(acc[i2][2] + bz[2], 0.f);
        o0.w = fmaxf(acc[i2][3] + bz[3], 0.f);
        o1.x = fmaxf(acc[i2][4] + bz[4], 0.f);
        o1.y = fmaxf(acc[i2][5] + bz[5], 0.f);
        o1.z = fmaxf(acc[i2][6] + bz[6], 0.f);
        o1.w = fmaxf(acc[i2][7] + bz[7], 0.f);
        *reinterpret_cast<float4*>(&C1[(size_t)row * N1 + cbase]) = o0;
        *reinterpret_cast<float4*>(&C1[(size_t)row * N1 + cbase + 4]) = o1;
    }
}

// ---------------- GEMM2: C2 += C1 @ fc2_w  (split-K, atomic accumulate) ----------------
// M=2048, K=2048 (split 8x256), N=100. BM=64, 8 rows x 4 cols per thread.
__global__ __launch_bounds__(256) void k_gemm2(const float* __restrict__ C1,
                                               const float* __restrict__ W,  // (2048,100)
                                               float* __restrict__ C2) {
    __shared__ float As[16][68];    // transposed, pad 68 -> 2-way store banks
    __shared__ float Bs[16][132];   // 100 cols + safety pad for clamp lanes
    const int tid = threadIdx.x;
    const int bm = blockIdx.x * 64;
    const int k_base = blockIdx.y * 256;
    const int rt = tid >> 5;  // 0..7  -> rows rt*8..+7
    const int ct = tid & 31;  // 0..31 -> cols ct*4..+3 (ct<25 valid)
    float acc[8][4] = {};

    for (int k0 = k_base; k0 < k_base + 256; k0 += 16) {
        {   // stage A: 64 x 16 = 256 float4, 1 per thread
            int r = tid >> 2;
            int k4 = (tid & 3) << 2;
            float4 v = *reinterpret_cast<const float4*>(C1 + (size_t)(bm + r) * N1 + k0 + k4);
            As[k4 + 0][r] = v.x;
            As[k4 + 1][r] = v.y;
            As[k4 + 2][r] = v.z;
            As[k4 + 3][r] = v.w;
        }
        // stage B: 16 x 100 = 400 float4
#pragma unroll
        for (int h = 0; h < 2; ++h) {
            int i = tid + h * 256;
            if (i < 400) {
                int kk = i / 25;
                int c4 = (i % 25) * 4;
                *reinterpret_cast<float4*>(&Bs[kk][c4]) =
                    *reinterpret_cast<const float4*>(W + (size_t)(k0 + kk) * N2 + c4);
            }
        }
        __syncthreads();
        int cc = (ct < 25) ? ct * 4 : 100;   // clamp lanes read pad (discarded)
#pragma unroll
        for (int kk = 0; kk < 16; ++kk) {
            float4 a0 = *reinterpret_cast<const float4*>(&As[kk][rt * 8]);
            float4 a1 = *reinterpret_cast<const float4*>(&As[kk][rt * 8 + 4]);
            float4 b = *reinterpret_cast<const float4*>(&Bs[kk][cc]);
            float a[8] = {a0.x, a0.y, a0.z, a0.w, a1.x, a1.y, a1.z, a1.w};
#pragma unroll
            for (int i2 = 0; i2 < 8; ++i2) {
                acc[i2][0] = fmaf(a[i2], b.x, acc[i2][0]);
                acc[i2][1] = fmaf(a[i2], b.y, acc[i2][1]);
                acc[i2][2] = fmaf(a[i2], b.z, acc[i2][2]);
                acc[i2][3] = fmaf(a[i2], b.w, acc[i2][3]);
            }
        }
        __syncthreads();
    }
    if (ct < 25) {
#pragma unroll
        for (int i2 = 0; i2 < 8; ++i2) {
            float* p = C2 + (size_t)(bm + rt * 8 + i2) * N2 + ct * 4;
            atomicAdd(p + 0, acc[i2][0]);
            atomicAdd(p + 1, acc[i2][1]);
            atomicAdd(p + 2, acc[i2][2]);
            atomicAdd(p + 3, acc[i2][3]);
        }
    }
}

// ---------------- r2 + MLP: one wave per batch row ----------------
__global__ __launch_bounds__(64) void k_r2mlp(const float* __restrict__ C2,
                                              const float* __restrict__ fc2b,
                                              const float* __restrict__ others,
                                              const float* __restrict__ m1w,
                                              const float* __restrict__ m1b,
                                              const float* __restrict__ m2w,
                                              const float* __restrict__ m2b,
                                              float* __restrict__ out) {
    const int b = blockIdx.x;
    const int t = threadIdx.x;
    float v1a, v2a, v1b = 0.f, v2b = 0.f;
    {
        float bb = fc2b[t];   // t < 64 < 100
        v1a = C2[(size_t)b * N2 + t] + bb;
        v2a = C2[(size_t)(b + BATCH) * N2 + t] + bb;
    }
    const bool sec = (t + 64) < N2;   // t < 36
    if (sec) {
        float bb = fc2b[t + 64];
        v1b = C2[(size_t)b * N2 + t + 64] + bb;
        v2b = C2[(size_t)(b + BATCH) * N2 + t + 64] + bb;
    }
    float s1 = v1a + v1b, s2 = v2a + v2b;
#pragma unroll
    for (int o = 32; o; o >>= 1) {
        s1 += __shfl_xor(s1, o, 64);
        s2 += __shfl_xor(s2, o, 64);
    }
    const float inv = 1.0f / (float)N2;
    float m1 = s1 * inv, m2 = s2 * inv;
    float c1a = v1a - m1, c2a = v2a - m2;
    float c1b = sec ? v1b - m1 : 0.f, c2b = sec ? v2b - m2 : 0.f;
    float num = c1a * c2a + c1b * c2b;
    float d1 = c1a * c1a + c1b * c1b;
    float d2 = c2a * c2a + c2b * c2b;
#pragma unroll
    for (int o = 32; o; o >>= 1) {
        num += __shfl_xor(num, o, 64);
        d1 += __shfl_xor(d1, o, 64);
        d2 += __shfl_xor(d2, o, 64);
    }
    if (t == 0) {
        float r = num / (sqrtf(d1) * sqrtf(d2));
        float r2 = r * r;
        float z[5] = {r2, others[b * 4 + 0], others[b * 4 + 1], others[b * 4 + 2], others[b * 4 + 3]};
        float h[4];
#pragma unroll
        for (int j = 0; j < 4; ++j) {
            float a = m1b[j];
#pragma unroll
            for (int i = 0; i < 5; ++i) a = fmaf(z[i], m1w[i * 4 + j], a);
            h[j] = fmaxf(a, 0.f);
        }
#pragma unroll
        for (int o = 0; o < 2; ++o) {
            float a = m2b[o];
#pragma unroll
            for (int j = 0; j < 4; ++j) a = fmaf(h[j], m2w[j * 2 + o], a);
            out[b * 2 + o] = a;
        }
    }
}

extern "C" void kernel_launch(void* const* d_in, const int* in_sizes, int n_in,
                              void* d_out, int out_size, void* d_ws, size_t ws_size,
                              hipStream_t stream) {
    const float* x1    = (const float*)d_in[0];
    const float* x2    = (const float*)d_in[1];
    const int*   edges = (const int*)d_in[2];
    const float* oth   = (const float*)d_in[3];
    const float* gw    = (const float*)d_in[4];
    const float* gb    = (const float*)d_in[5];
    const float* fc1w  = (const float*)d_in[6];
    const float* fc1b  = (const float*)d_in[7];
    const float* fc2w  = (const float*)d_in[8];
    const float* fc2b  = (const float*)d_in[9];
    const float* m1w   = (const float*)d_in[10];
    const float* m1b   = (const float*)d_in[11];
    const float* m2w   = (const float*)d_in[12];
    const float* m2b   = (const float*)d_in[13];

    float* ws  = (float*)d_ws;
    float* agg = ws + OFF_AGG;
    float* C2  = ws + OFF_C2;
    float* xi  = ws + OFF_XI;
    float* C1  = ws + OFF_C1;
    float* out = (float*)d_out;

    // zero agg (+padding cols) and C2 (contiguous region)
    hipMemsetAsync(agg, 0, (size_t)(MR * KPAD + MR * N2) * sizeof(float), stream);

    k_interleave<<<(NNODES / 4 + 255) / 256, 256, 0, stream>>>(x1, x2, xi);
    k_edges<<<NEDGES / 4 / 256, 256, 0, stream>>>(edges, xi, agg);
    k_gemm1<<<dim3(16, 16), 256, 0, stream>>>(agg, fc1w, fc1b, gw, gb, C1);
    k_gemm2<<<dim3(32, 8), 256, 0, stream>>>(C1, fc2w, C2);
    k_r2mlp<<<1024, 64, 0, stream>>>(C2, fc2b, oth, m1w, m1b, m2w, m2b, out);
}

// Round 2
// 1064.840 us; speedup vs baseline: 2.2886x; 2.2886x over previous
//
#include <hip/hip_runtime.h>

#define NG 978
#define BATCH 1024
#define MR 2048            // 2*BATCH stacked rows (enc1 rows 0..1023, enc2 1024..2047)
#define KPAD 1024          // padded K stride for agg (zero-padded cols 978..1023)
#define NEDGES 20480000
#define NNODES (BATCH * NG)   // 1001472 = 978 buckets * 1024 nodes
#define N1 2048            // fc1 out
#define N2 100             // fc2 out
#define NBKT 978
#define BCAP 24576         // bucket capacity: mean 20941 + ~25 sigma

// ws layout in floats:
// [agg (MR*KPAD) | C2 (MR*N2) | CUR (1024) | xi (2*NNODES) | C1 (MR*N1) | aggN (2*NNODES) | BKT (NBKT*BCAP)]
#define OFF_AGG 0
#define OFF_C2  (OFF_AGG + MR * KPAD)          // 2,097,152
#define OFF_CUR (OFF_C2 + MR * N2)             // 2,301,952
#define OFF_XI  (OFF_CUR + 1024)               // 2,302,976
#define OFF_C1  (OFF_XI + 2 * NNODES)          // 4,305,920
#define OFF_AGGN (OFF_C1 + MR * N1)            // 8,500,224
#define OFF_BKT (OFF_AGGN + 2 * NNODES)        // 10,503,168
#define OFF_END (OFF_BKT + NBKT * BCAP)        // 34,538,496 floats = ~132 MB
#define NEED_BYTES ((size_t)OFF_END * 4)

// ---------------- interleave x1,x2 -> xi (float2 per node) ----------------
__global__ __launch_bounds__(256) void k_interleave(const float* __restrict__ x1,
                                                    const float* __restrict__ x2,
                                                    float* __restrict__ xi) {
    int i = blockIdx.x * 256 + threadIdx.x;   // float4 group index
    if (i >= NNODES / 4) return;
    float4 a = reinterpret_cast<const float4*>(x1)[i];
    float4 b = reinterpret_cast<const float4*>(x2)[i];
    float4 lo = make_float4(a.x, b.x, a.y, b.y);
    float4 hi = make_float4(a.z, b.z, a.w, b.w);
    reinterpret_cast<float4*>(xi)[2 * i + 0] = lo;
    reinterpret_cast<float4*>(xi)[2 * i + 1] = hi;
}

// ---------------- bin edges by dst bucket (dst>>10), packed (src<<10)|dstLow ----------------
// 625 blocks x 32768 edges. Per-block LDS histogram -> one global cursor reservation
// per (block,bucket) -> packed writes. No per-edge global atomics.
__global__ __launch_bounds__(256) void k_scatter(const int* __restrict__ edges,
                                                 int* __restrict__ cursor,
                                                 unsigned* __restrict__ bkt) {
    __shared__ int cnt[1024];
    __shared__ int lbase[1024];
    __shared__ int lcur[1024];
    const int t = threadIdx.x;
    const int chunk = blockIdx.x * 32768;
    for (int i = t; i < 1024; i += 256) { cnt[i] = 0; lcur[i] = 0; }
    __syncthreads();
    const int4* d4 = reinterpret_cast<const int4*>(edges + NEDGES + chunk);
    const int4* s4 = reinterpret_cast<const int4*>(edges + chunk);
#pragma unroll 4
    for (int j = 0; j < 32; ++j) {
        int4 d = d4[t + j * 256];
        atomicAdd(&cnt[d.x >> 10], 1);
        atomicAdd(&cnt[d.y >> 10], 1);
        atomicAdd(&cnt[d.z >> 10], 1);
        atomicAdd(&cnt[d.w >> 10], 1);
    }
    __syncthreads();
    for (int b = t; b < NBKT; b += 256) {
        if (cnt[b]) lbase[b] = atomicAdd(&cursor[b], cnt[b]);
    }
    __syncthreads();
#pragma unroll 4
    for (int j = 0; j < 32; ++j) {
        int4 d = d4[t + j * 256];
        int4 s = s4[t + j * 256];
        int dd[4] = {d.x, d.y, d.z, d.w};
        int ss[4] = {s.x, s.y, s.z, s.w};
#pragma unroll
        for (int u = 0; u < 4; ++u) {
            int b = dd[u] >> 10;
            int r = atomicAdd(&lcur[b], 1);
            int slot = lbase[b] + r;
            if (slot < BCAP)   // statistically impossible overflow guard
                bkt[(size_t)b * BCAP + slot] = ((unsigned)ss[u] << 10) | (unsigned)(dd[u] & 1023);
        }
    }
}

// ---------------- accumulate: one block per bucket, LDS accumulation ----------------
__global__ __launch_bounds__(256) void k_accum(const unsigned* __restrict__ bkt,
                                               const int* __restrict__ cursor,
                                               const float* __restrict__ xi,
                                               float* __restrict__ aggN) {
    __shared__ float accX[1024];
    __shared__ float accY[1024];
    const int b = blockIdx.x;
    const int t = threadIdx.x;
    for (int i = t; i < 1024; i += 256) { accX[i] = 0.f; accY[i] = 0.f; }
    __syncthreads();
    const int n = cursor[b];
    const unsigned* bp = bkt + (size_t)b * BCAP;
    const float2* xi2 = reinterpret_cast<const float2*>(xi);
    int i = t;
    for (; i + 256 < n; i += 512) {
        unsigned p0 = bp[i];
        unsigned p1 = bp[i + 256];
        float2 v0 = xi2[p0 >> 10];
        float2 v1 = xi2[p1 >> 10];
        atomicAdd(&accX[p0 & 1023], v0.x);
        atomicAdd(&accY[p0 & 1023], v0.y);
        atomicAdd(&accX[p1 & 1023], v1.x);
        atomicAdd(&accY[p1 & 1023], v1.y);
    }
    if (i < n) {
        unsigned p0 = bp[i];
        float2 v0 = xi2[p0 >> 10];
        atomicAdd(&accX[p0 & 1023], v0.x);
        atomicAdd(&accY[p0 & 1023], v0.y);
    }
    __syncthreads();
    float2* o = reinterpret_cast<float2*>(aggN) + ((size_t)b << 10);
    for (int j = t; j < 1024; j += 256) o[j] = make_float2(accX[j], accY[j]);
}

// ---------------- reshape node-indexed aggN -> two padded planes ----------------
__global__ __launch_bounds__(256) void k_reshape(const float* __restrict__ aggN,
                                                 float* __restrict__ agg) {
    int idx = blockIdx.x * 256 + threadIdx.x;   // BATCH * KPAD/4 = 262144
    int row = idx >> 8;
    int c4 = (idx & 255) << 2;
    const float2* a2 = reinterpret_cast<const float2*>(aggN);
    float4 vx = make_float4(0.f, 0.f, 0.f, 0.f);
    float4 vy = make_float4(0.f, 0.f, 0.f, 0.f);
    float* px = &vx.x;
    float* py = &vy.x;
#pragma unroll
    for (int u = 0; u < 4; ++u) {
        int col = c4 + u;
        if (col < NG) {
            float2 v = a2[(size_t)row * NG + col];
            px[u] = v.x;
            py[u] = v.y;
        }
    }
    *reinterpret_cast<float4*>(&agg[(size_t)row * KPAD + c4]) = vx;
    *reinterpret_cast<float4*>(&agg[(size_t)(BATCH + row) * KPAD + c4]) = vy;
}

// ---------------- fallback edge kernel (round-0 path, used if ws too small) ----------------
__global__ __launch_bounds__(256) void k_edges(const int* __restrict__ edges,
                                               const float* __restrict__ xi,
                                               float* __restrict__ agg) {
    int t = blockIdx.x * 256 + threadIdx.x;
    int e = t * 4;
    const int4 s4 = *reinterpret_cast<const int4*>(edges + e);
    const int4 d4 = *reinterpret_cast<const int4*>(edges + NEDGES + e);
    int ss[4] = {s4.x, s4.y, s4.z, s4.w};
    int dd[4] = {d4.x, d4.y, d4.z, d4.w};
#pragma unroll
    for (int j = 0; j < 4; ++j) {
        int s = ss[j];
        int d = dd[j];
        float2 xv = *reinterpret_cast<const float2*>(xi + 2 * (size_t)s);
        int row = d / NG;
        int col = d - row * NG;
        float* p = agg + (size_t)row * KPAD + col;
        atomicAdd(p, xv.x);
        atomicAdd(p + (size_t)BATCH * KPAD, xv.y);
    }
}

// ---------------- GEMM1: C1 = relu( relu(agg*gw+gb) @ W + bias ) ----------------
__global__ __launch_bounds__(256) void k_gemm1(const float* __restrict__ agg,
                                               const float* __restrict__ W,    // (978,2048)
                                               const float* __restrict__ bias, // (2048)
                                               const float* __restrict__ gwp,
                                               const float* __restrict__ gbp,
                                               float* __restrict__ C1) {
    __shared__ float As[16][132];
    __shared__ float Bs[16][132];
    const int tid = threadIdx.x;
    const int bm = blockIdx.y * 128;
    const int bn = blockIdx.x * 128;
    const float gw = gwp[0], gb = gbp[0];
    const int rt = tid >> 4;
    const int ct = tid & 15;

    float acc[8][8] = {};

    for (int k0 = 0; k0 < NG; k0 += 16) {
#pragma unroll
        for (int h = 0; h < 2; ++h) {
            int i = tid + h * 256;
            int r = i >> 2;
            int k4 = (i & 3) << 2;
            float4 v = *reinterpret_cast<const float4*>(agg + (size_t)(bm + r) * KPAD + k0 + k4);
            v.x = fmaxf(v.x * gw + gb, 0.f);
            v.y = fmaxf(v.y * gw + gb, 0.f);
            v.z = fmaxf(v.z * gw + gb, 0.f);
            v.w = fmaxf(v.w * gw + gb, 0.f);
            As[k4 + 0][r] = v.x;
            As[k4 + 1][r] = v.y;
            As[k4 + 2][r] = v.z;
            As[k4 + 3][r] = v.w;
        }
#pragma unroll
        for (int h = 0; h < 2; ++h) {
            int i = tid + h * 256;
            int row = i >> 5;
            int c4 = (i & 31) << 2;
            int gk = k0 + row;
            float4 v = make_float4(0.f, 0.f, 0.f, 0.f);
            if (gk < NG) v = *reinterpret_cast<const float4*>(W + (size_t)gk * N1 + bn + c4);
            int pc = c4 + ((c4 >> 6) << 2);
            *reinterpret_cast<float4*>(&Bs[row][pc]) = v;
        }
        __syncthreads();
#pragma unroll
        for (int kk = 0; kk < 16; ++kk) {
            float4 a0 = *reinterpret_cast<const float4*>(&As[kk][rt * 8]);
            float4 a1 = *reinterpret_cast<const float4*>(&As[kk][rt * 8 + 4]);
            int cb = ct * 8;
            int pc = cb + ((cb >> 6) << 2);
            float4 b0 = *reinterpret_cast<const float4*>(&Bs[kk][pc]);
            float4 b1 = *reinterpret_cast<const float4*>(&Bs[kk][pc + 4]);
            float a[8] = {a0.x, a0.y, a0.z, a0.w, a1.x, a1.y, a1.z, a1.w};
            float b[8] = {b0.x, b0.y, b0.z, b0.w, b1.x, b1.y, b1.z, b1.w};
#pragma unroll
            for (int i2 = 0; i2 < 8; ++i2)
#pragma unroll
                for (int j2 = 0; j2 < 8; ++j2)
                    acc[i2][j2] = fmaf(a[i2], b[j2], acc[i2][j2]);
        }
        __syncthreads();
    }
    const int cbase = bn + ct * 8;
    float4 bb0 = *reinterpret_cast<const float4*>(&bias[cbase]);
    float4 bb1 = *reinterpret_cast<const float4*>(&bias[cbase + 4]);
    float bz[8] = {bb0.x, bb0.y, bb0.z, bb0.w, bb1.x, bb1.y, bb1.z, bb1.w};
#pragma unroll
    for (int i2 = 0; i2 < 8; ++i2) {
        int row = bm + rt * 8 + i2;
        float4 o0, o1;
        o0.x = fmaxf(acc[i2][0] + bz[0], 0.f);
        o0.y = fmaxf(acc[i2][1] + bz[1], 0.f);
        o0.z = fmaxf(acc[i2][2] + bz[2], 0.f);
        o0.w = fmaxf(acc[i2][3] + bz[3], 0.f);
        o1.x = fmaxf(acc[i2][4] + bz[4], 0.f);
        o1.y = fmaxf(acc[i2][5] + bz[5], 0.f);
        o1.z = fmaxf(acc[i2][6] + bz[6], 0.f);
        o1.w = fmaxf(acc[i2][7] + bz[7], 0.f);
        *reinterpret_cast<float4*>(&C1[(size_t)row * N1 + cbase]) = o0;
        *reinterpret_cast<float4*>(&C1[(size_t)row * N1 + cbase + 4]) = o1;
    }
}

// ---------------- GEMM2: C2 += C1 @ fc2_w  (split-K, atomic accumulate) ----------------
__global__ __launch_bounds__(256) void k_gemm2(const float* __restrict__ C1,
                                               const float* __restrict__ W,  // (2048,100)
                                               float* __restrict__ C2) {
    __shared__ float As[16][68];
    __shared__ float Bs[16][132];
    const int tid = threadIdx.x;
    const int bm = blockIdx.x * 64;
    const int k_base = blockIdx.y * 256;
    const int rt = tid >> 5;
    const int ct = tid & 31;
    float acc[8][4] = {};

    for (int k0 = k_base; k0 < k_base + 256; k0 += 16) {
        {
            int r = tid >> 2;
            int k4 = (tid & 3) << 2;
            float4 v = *reinterpret_cast<const float4*>(C1 + (size_t)(bm + r) * N1 + k0 + k4);
            As[k4 + 0][r] = v.x;
            As[k4 + 1][r] = v.y;
            As[k4 + 2][r] = v.z;
            As[k4 + 3][r] = v.w;
        }
#pragma unroll
        for (int h = 0; h < 2; ++h) {
            int i = tid + h * 256;
            if (i < 400) {
                int kk = i / 25;
                int c4 = (i % 25) * 4;
                *reinterpret_cast<float4*>(&Bs[kk][c4]) =
                    *reinterpret_cast<const float4*>(W + (size_t)(k0 + kk) * N2 + c4);
            }
        }
        __syncthreads();
        int cc = (ct < 25) ? ct * 4 : 100;
#pragma unroll
        for (int kk = 0; kk < 16; ++kk) {
            float4 a0 = *reinterpret_cast<const float4*>(&As[kk][rt * 8]);
            float4 a1 = *reinterpret_cast<const float4*>(&As[kk][rt * 8 + 4]);
            float4 b = *reinterpret_cast<const float4*>(&Bs[kk][cc]);
            float a[8] = {a0.x, a0.y, a0.z, a0.w, a1.x, a1.y, a1.z, a1.w};
#pragma unroll
            for (int i2 = 0; i2 < 8; ++i2) {
                acc[i2][0] = fmaf(a[i2], b.x, acc[i2][0]);
                acc[i2][1] = fmaf(a[i2], b.y, acc[i2][1]);
                acc[i2][2] = fmaf(a[i2], b.z, acc[i2][2]);
                acc[i2][3] = fmaf(a[i2], b.w, acc[i2][3]);
            }
        }
        __syncthreads();
    }
    if (ct < 25) {
#pragma unroll
        for (int i2 = 0; i2 < 8; ++i2) {
            float* p = C2 + (size_t)(bm + rt * 8 + i2) * N2 + ct * 4;
            atomicAdd(p + 0, acc[i2][0]);
            atomicAdd(p + 1, acc[i2][1]);
            atomicAdd(p + 2, acc[i2][2]);
            atomicAdd(p + 3, acc[i2][3]);
        }
    }
}

// ---------------- r2 + MLP: one wave per batch row ----------------
__global__ __launch_bounds__(64) void k_r2mlp(const float* __restrict__ C2,
                                              const float* __restrict__ fc2b,
                                              const float* __restrict__ others,
                                              const float* __restrict__ m1w,
                                              const float* __restrict__ m1b,
                                              const float* __restrict__ m2w,
                                              const float* __restrict__ m2b,
                                              float* __restrict__ out) {
    const int b = blockIdx.x;
    const int t = threadIdx.x;
    float v1a, v2a, v1b = 0.f, v2b = 0.f;
    {
        float bb = fc2b[t];
        v1a = C2[(size_t)b * N2 + t] + bb;
        v2a = C2[(size_t)(b + BATCH) * N2 + t] + bb;
    }
    const bool sec = (t + 64) < N2;
    if (sec) {
        float bb = fc2b[t + 64];
        v1b = C2[(size_t)b * N2 + t + 64] + bb;
        v2b = C2[(size_t)(b + BATCH) * N2 + t + 64] + bb;
    }
    float s1 = v1a + v1b, s2 = v2a + v2b;
#pragma unroll
    for (int o = 32; o; o >>= 1) {
        s1 += __shfl_xor(s1, o, 64);
        s2 += __shfl_xor(s2, o, 64);
    }
    const float inv = 1.0f / (float)N2;
    float m1 = s1 * inv, m2 = s2 * inv;
    float c1a = v1a - m1, c2a = v2a - m2;
    float c1b = sec ? v1b - m1 : 0.f, c2b = sec ? v2b - m2 : 0.f;
    float num = c1a * c2a + c1b * c2b;
    float d1 = c1a * c1a + c1b * c1b;
    float d2 = c2a * c2a + c2b * c2b;
#pragma unroll
    for (int o = 32; o; o >>= 1) {
        num += __shfl_xor(num, o, 64);
        d1 += __shfl_xor(d1, o, 64);
        d2 += __shfl_xor(d2, o, 64);
    }
    if (t == 0) {
        float r = num / (sqrtf(d1) * sqrtf(d2));
        float r2 = r * r;
        float z[5] = {r2, others[b * 4 + 0], others[b * 4 + 1], others[b * 4 + 2], others[b * 4 + 3]};
        float h[4];
#pragma unroll
        for (int j = 0; j < 4; ++j) {
            float a = m1b[j];
#pragma unroll
            for (int i = 0; i < 5; ++i) a = fmaf(z[i], m1w[i * 4 + j], a);
            h[j] = fmaxf(a, 0.f);
        }
#pragma unroll
        for (int o = 0; o < 2; ++o) {
            float a = m2b[o];
#pragma unroll
            for (int j = 0; j < 4; ++j) a = fmaf(h[j], m2w[j * 2 + o], a);
            out[b * 2 + o] = a;
        }
    }
}

extern "C" void kernel_launch(void* const* d_in, const int* in_sizes, int n_in,
                              void* d_out, int out_size, void* d_ws, size_t ws_size,
                              hipStream_t stream) {
    const float* x1    = (const float*)d_in[0];
    const float* x2    = (const float*)d_in[1];
    const int*   edges = (const int*)d_in[2];
    const float* oth   = (const float*)d_in[3];
    const float* gw    = (const float*)d_in[4];
    const float* gb    = (const float*)d_in[5];
    const float* fc1w  = (const float*)d_in[6];
    const float* fc1b  = (const float*)d_in[7];
    const float* fc2w  = (const float*)d_in[8];
    const float* fc2b  = (const float*)d_in[9];
    const float* m1w   = (const float*)d_in[10];
    const float* m1b   = (const float*)d_in[11];
    const float* m2w   = (const float*)d_in[12];
    const float* m2b   = (const float*)d_in[13];

    float* ws   = (float*)d_ws;
    float* agg  = ws + OFF_AGG;
    float* C2   = ws + OFF_C2;
    int*   cur  = (int*)(ws + OFF_CUR);
    float* xi   = ws + OFF_XI;
    float* C1   = ws + OFF_C1;
    float* aggN = ws + OFF_AGGN;
    unsigned* bkt = (unsigned*)(ws + OFF_BKT);
    float* out = (float*)d_out;

    k_interleave<<<(NNODES / 4 + 255) / 256, 256, 0, stream>>>(x1, x2, xi);

    if (ws_size >= NEED_BYTES) {
        // C2 + cursors zeroed in one contiguous memset; agg fully written by k_reshape
        hipMemsetAsync(C2, 0, (size_t)(MR * N2 + 1024) * sizeof(float), stream);
        k_scatter<<<NEDGES / 32768, 256, 0, stream>>>(edges, cur, bkt);
        k_accum<<<NBKT, 256, 0, stream>>>(bkt, cur, xi, aggN);
        k_reshape<<<BATCH * (KPAD / 4) / 256, 256, 0, stream>>>(aggN, agg);
    } else {
        // fallback: round-0 atomic path (agg+C2 contiguous memset)
        hipMemsetAsync(agg, 0, (size_t)(MR * KPAD + MR * N2) * sizeof(float), stream);
        k_edges<<<NEDGES / 4 / 256, 256, 0, stream>>>(edges, xi, agg);
    }

    k_gemm1<<<dim3(16, 16), 256, 0, stream>>>(agg, fc1w, fc1b, gw, gb, C1);
    k_gemm2<<<dim3(32, 8), 256, 0, stream>>>(C1, fc2w, C2);
    k_r2mlp<<<1024, 64, 0, stream>>>(C2, fc2b, oth, m1w, m1b, m2w, m2b, out);
}

// Round 3
// 1055.366 us; speedup vs baseline: 2.3091x; 1.0090x over previous
//
#include <hip/hip_runtime.h>

#define NG 978
#define BATCH 1024
#define MR 2048            // 2*BATCH stacked rows (enc1 rows 0..1023, enc2 1024..2047)
#define KPAD 1024          // padded K stride for agg (zero-padded cols 978..1023)
#define NEDGES 20480000
#define NNODES (BATCH * NG)   // 1001472 = 978 buckets * 1024 nodes
#define N1 2048            // fc1 out
#define N2 100             // fc2 out
#define NBKT 978
#define BCAP 24576         // bucket capacity: mean 20941 + ~25 sigma
#define SCHUNK 8192        // edges per scatter block (2500 blocks -> ~10/CU)

// ws layout in floats:
// [agg (MR*KPAD) | C2 (MR*N2) | CUR (1024) | xi (2*NNODES) | C1 (MR*N1) | aggN (2*NNODES) | BKT (NBKT*BCAP)]
#define OFF_AGG 0
#define OFF_C2  (OFF_AGG + MR * KPAD)          // 2,097,152
#define OFF_CUR (OFF_C2 + MR * N2)             // 2,301,952
#define OFF_XI  (OFF_CUR + 1024)               // 2,302,976
#define OFF_C1  (OFF_XI + 2 * NNODES)          // 4,305,920
#define OFF_AGGN (OFF_C1 + MR * N1)            // 8,500,224
#define OFF_BKT (OFF_AGGN + 2 * NNODES)        // 10,503,168
#define OFF_END (OFF_BKT + NBKT * BCAP)        // 34,538,496 floats = ~132 MB
#define NEED_BYTES ((size_t)OFF_END * 4)

// ---------------- interleave x1,x2 -> xi (float2 per node) ----------------
__global__ __launch_bounds__(256) void k_interleave(const float* __restrict__ x1,
                                                    const float* __restrict__ x2,
                                                    float* __restrict__ xi) {
    int i = blockIdx.x * 256 + threadIdx.x;   // float4 group index
    if (i >= NNODES / 4) return;
    float4 a = reinterpret_cast<const float4*>(x1)[i];
    float4 b = reinterpret_cast<const float4*>(x2)[i];
    float4 lo = make_float4(a.x, b.x, a.y, b.y);
    float4 hi = make_float4(a.z, b.z, a.w, b.w);
    reinterpret_cast<float4*>(xi)[2 * i + 0] = lo;
    reinterpret_cast<float4*>(xi)[2 * i + 1] = hi;
}

// ---------------- bin edges by dst bucket (dst>>10), packed (src<<10)|dstLow ----------------
// 2500 blocks x 8192 edges. Per-block LDS histogram -> one global cursor reservation
// per (block,bucket) -> packed writes. No per-edge global atomics.
__global__ __launch_bounds__(256) void k_scatter(const int* __restrict__ edges,
                                                 int* __restrict__ cursor,
                                                 unsigned* __restrict__ bkt) {
    __shared__ int cnt[1024];
    __shared__ int lbase[1024];
    __shared__ int lcur[1024];
    const int t = threadIdx.x;
    const int chunk = blockIdx.x * SCHUNK;
    for (int i = t; i < 1024; i += 256) { cnt[i] = 0; lcur[i] = 0; }
    __syncthreads();
    const int4* d4 = reinterpret_cast<const int4*>(edges + NEDGES + chunk);
    const int4* s4 = reinterpret_cast<const int4*>(edges + chunk);
#pragma unroll
    for (int j = 0; j < SCHUNK / 1024; ++j) {   // 8
        int4 d = d4[t + j * 256];
        atomicAdd(&cnt[d.x >> 10], 1);
        atomicAdd(&cnt[d.y >> 10], 1);
        atomicAdd(&cnt[d.z >> 10], 1);
        atomicAdd(&cnt[d.w >> 10], 1);
    }
    __syncthreads();
    for (int b = t; b < NBKT; b += 256) {
        if (cnt[b]) lbase[b] = atomicAdd(&cursor[b], cnt[b]);
    }
    __syncthreads();
#pragma unroll
    for (int j = 0; j < SCHUNK / 1024; ++j) {
        int4 d = d4[t + j * 256];
        int4 s = s4[t + j * 256];
        int dd[4] = {d.x, d.y, d.z, d.w};
        int ss[4] = {s.x, s.y, s.z, s.w};
#pragma unroll
        for (int u = 0; u < 4; ++u) {
            int b = dd[u] >> 10;
            int r = atomicAdd(&lcur[b], 1);
            int slot = lbase[b] + r;
            if (slot < BCAP)   // statistically impossible overflow guard
                bkt[(size_t)b * BCAP + slot] = ((unsigned)ss[u] << 10) | (unsigned)(dd[u] & 1023);
        }
    }
}

// ---------------- accumulate: two blocks per bucket (edge-range split), LDS accumulation,
// coalesced atomic merge into zeroed aggN ----------------
__global__ __launch_bounds__(256) void k_accum(const unsigned* __restrict__ bkt,
                                               const int* __restrict__ cursor,
                                               const float* __restrict__ xi,
                                               float* __restrict__ aggN) {
    __shared__ float accX[1024];
    __shared__ float accY[1024];
    const int b = blockIdx.x >> 1;
    const int h = blockIdx.x & 1;
    const int t = threadIdx.x;
    for (int i = t; i < 1024; i += 256) { accX[i] = 0.f; accY[i] = 0.f; }
    __syncthreads();
    const int n = cursor[b];
    const int half = (n + 1) >> 1;
    const int lo = h ? half : 0;
    const int hi = h ? n : half;
    const unsigned* bp = bkt + (size_t)b * BCAP;
    const float2* xi2 = reinterpret_cast<const float2*>(xi);
    int i = lo + t;
    for (; i + 256 < hi; i += 512) {
        unsigned p0 = bp[i];
        unsigned p1 = bp[i + 256];
        float2 v0 = xi2[p0 >> 10];
        float2 v1 = xi2[p1 >> 10];
        atomicAdd(&accX[p0 & 1023], v0.x);
        atomicAdd(&accY[p0 & 1023], v0.y);
        atomicAdd(&accX[p1 & 1023], v1.x);
        atomicAdd(&accY[p1 & 1023], v1.y);
    }
    if (i < hi) {
        unsigned p0 = bp[i];
        float2 v0 = xi2[p0 >> 10];
        atomicAdd(&accX[p0 & 1023], v0.x);
        atomicAdd(&accY[p0 & 1023], v0.y);
    }
    __syncthreads();
    float* o = aggN + ((size_t)b << 11);
    for (int j = t; j < 1024; j += 256) {
        atomicAdd(o + 2 * j + 0, accX[j]);
        atomicAdd(o + 2 * j + 1, accY[j]);
    }
}

// ---------------- reshape node-indexed aggN -> two padded planes ----------------
__global__ __launch_bounds__(256) void k_reshape(const float* __restrict__ aggN,
                                                 float* __restrict__ agg) {
    int idx = blockIdx.x * 256 + threadIdx.x;   // BATCH * KPAD/4 = 262144
    int row = idx >> 8;
    int c4 = (idx & 255) << 2;
    const float2* a2 = reinterpret_cast<const float2*>(aggN);
    float4 vx = make_float4(0.f, 0.f, 0.f, 0.f);
    float4 vy = make_float4(0.f, 0.f, 0.f, 0.f);
    float* px = &vx.x;
    float* py = &vy.x;
#pragma unroll
    for (int u = 0; u < 4; ++u) {
        int col = c4 + u;
        if (col < NG) {
            float2 v = a2[(size_t)row * NG + col];
            px[u] = v.x;
            py[u] = v.y;
        }
    }
    *reinterpret_cast<float4*>(&agg[(size_t)row * KPAD + c4]) = vx;
    *reinterpret_cast<float4*>(&agg[(size_t)(BATCH + row) * KPAD + c4]) = vy;
}

// ---------------- fallback edge kernel (round-0 path, used if ws too small) ----------------
__global__ __launch_bounds__(256) void k_edges(const int* __restrict__ edges,
                                               const float* __restrict__ xi,
                                               float* __restrict__ agg) {
    int t = blockIdx.x * 256 + threadIdx.x;
    int e = t * 4;
    const int4 s4 = *reinterpret_cast<const int4*>(edges + e);
    const int4 d4 = *reinterpret_cast<const int4*>(edges + NEDGES + e);
    int ss[4] = {s4.x, s4.y, s4.z, s4.w};
    int dd[4] = {d4.x, d4.y, d4.z, d4.w};
#pragma unroll
    for (int j = 0; j < 4; ++j) {
        int s = ss[j];
        int d = dd[j];
        float2 xv = *reinterpret_cast<const float2*>(xi + 2 * (size_t)s);
        int row = d / NG;
        int col = d - row * NG;
        float* p = agg + (size_t)row * KPAD + col;
        atomicAdd(p, xv.x);
        atomicAdd(p + (size_t)BATCH * KPAD, xv.y);
    }
}

// ---------------- GEMM1: C1 = relu( relu(agg*gw+gb) @ W + bias ) ----------------
// M=2048, K=978 (stride 1024, zero-padded), N=2048. 128x128 tile, BK=16,
// 512 threads (8 waves -> 2/SIMD), 4x8 acc/thread.
__global__ __launch_bounds__(512) void k_gemm1(const float* __restrict__ agg,
                                               const float* __restrict__ W,    // (978,2048)
                                               const float* __restrict__ bias, // (2048)
                                               const float* __restrict__ gwp,
                                               const float* __restrict__ gbp,
                                               float* __restrict__ C1) {
    __shared__ float As[16][132];
    __shared__ float Bs[16][132];
    const int tid = threadIdx.x;
    const int bm = blockIdx.y * 128;
    const int bn = blockIdx.x * 128;
    const float gw = gwp[0], gb = gbp[0];
    const int rt = tid >> 4;   // 0..31 -> rows rt*4..+3
    const int ct = tid & 15;   // 0..15 -> cols ct*8..+7

    float acc[4][8] = {};

    for (int k0 = 0; k0 < NG; k0 += 16) {
        {   // stage A: 128 rows x 16 k = 512 float4, 1 per thread; affine+relu here
            int r = tid >> 2;
            int k4 = (tid & 3) << 2;
            float4 v = *reinterpret_cast<const float4*>(agg + (size_t)(bm + r) * KPAD + k0 + k4);
            v.x = fmaxf(v.x * gw + gb, 0.f);
            v.y = fmaxf(v.y * gw + gb, 0.f);
            v.z = fmaxf(v.z * gw + gb, 0.f);
            v.w = fmaxf(v.w * gw + gb, 0.f);
            As[k4 + 0][r] = v.x;
            As[k4 + 1][r] = v.y;
            As[k4 + 2][r] = v.z;
            As[k4 + 3][r] = v.w;
        }
        {   // stage B: 16 rows x 128 cols = 512 float4, 1 per thread (rows >= 978 zeroed)
            int row = tid >> 5;
            int c4 = (tid & 31) << 2;
            int gk = k0 + row;
            float4 v = make_float4(0.f, 0.f, 0.f, 0.f);
            if (gk < NG) v = *reinterpret_cast<const float4*>(W + (size_t)gk * N1 + bn + c4);
            int pc = c4 + ((c4 >> 6) << 2);
            *reinterpret_cast<float4*>(&Bs[row][pc]) = v;
        }
        __syncthreads();
#pragma unroll
        for (int kk = 0; kk < 16; ++kk) {
            float4 a0 = *reinterpret_cast<const float4*>(&As[kk][rt * 4]);
            int cb = ct * 8;
            int pc = cb + ((cb >> 6) << 2);
            float4 b0 = *reinterpret_cast<const float4*>(&Bs[kk][pc]);
            float4 b1 = *reinterpret_cast<const float4*>(&Bs[kk][pc + 4]);
            float a[4] = {a0.x, a0.y, a0.z, a0.w};
            float b[8] = {b0.x, b0.y, b0.z, b0.w, b1.x, b1.y, b1.z, b1.w};
#pragma unroll
            for (int i2 = 0; i2 < 4; ++i2)
#pragma unroll
                for (int j2 = 0; j2 < 8; ++j2)
                    acc[i2][j2] = fmaf(a[i2], b[j2], acc[i2][j2]);
        }
        __syncthreads();
    }
    const int cbase = bn + ct * 8;
    float4 bb0 = *reinterpret_cast<const float4*>(&bias[cbase]);
    float4 bb1 = *reinterpret_cast<const float4*>(&bias[cbase + 4]);
    float bz[8] = {bb0.x, bb0.y, bb0.z, bb0.w, bb1.x, bb1.y, bb1.z, bb1.w};
#pragma unroll
    for (int i2 = 0; i2 < 4; ++i2) {
        int row = bm + rt * 4 + i2;
        float4 o0, o1;
        o0.x = fmaxf(acc[i2][0] + bz[0], 0.f);
        o0.y = fmaxf(acc[i2][1] + bz[1], 0.f);
        o0.z = fmaxf(acc[i2][2] + bz[2], 0.f);
        o0.w = fmaxf(acc[i2][3] + bz[3], 0.f);
        o1.x = fmaxf(acc[i2][4] + bz[4], 0.f);
        o1.y = fmaxf(acc[i2][5] + bz[5], 0.f);
        o1.z = fmaxf(acc[i2][6] + bz[6], 0.f);
        o1.w = fmaxf(acc[i2][7] + bz[7], 0.f);
        *reinterpret_cast<float4*>(&C1[(size_t)row * N1 + cbase]) = o0;
        *reinterpret_cast<float4*>(&C1[(size_t)row * N1 + cbase + 4]) = o1;
    }
}

// ---------------- GEMM2: C2 += C1 @ fc2_w  (split-K, atomic accumulate) ----------------
__global__ __launch_bounds__(256) void k_gemm2(const float* __restrict__ C1,
                                               const float* __restrict__ W,  // (2048,100)
                                               float* __restrict__ C2) {
    __shared__ float As[16][68];
    __shared__ float Bs[16][132];
    const int tid = threadIdx.x;
    const int bm = blockIdx.x * 64;
    const int k_base = blockIdx.y * 256;
    const int rt = tid >> 5;
    const int ct = tid & 31;
    float acc[8][4] = {};

    for (int k0 = k_base; k0 < k_base + 256; k0 += 16) {
        {
            int r = tid >> 2;
            int k4 = (tid & 3) << 2;
            float4 v = *reinterpret_cast<const float4*>(C1 + (size_t)(bm + r) * N1 + k0 + k4);
            As[k4 + 0][r] = v.x;
            As[k4 + 1][r] = v.y;
            As[k4 + 2][r] = v.z;
            As[k4 + 3][r] = v.w;
        }
#pragma unroll
        for (int h = 0; h < 2; ++h) {
            int i = tid + h * 256;
            if (i < 400) {
                int kk = i / 25;
                int c4 = (i % 25) * 4;
                *reinterpret_cast<float4*>(&Bs[kk][c4]) =
                    *reinterpret_cast<const float4*>(W + (size_t)(k0 + kk) * N2 + c4);
            }
        }
        __syncthreads();
        int cc = (ct < 25) ? ct * 4 : 100;
#pragma unroll
        for (int kk = 0; kk < 16; ++kk) {
            float4 a0 = *reinterpret_cast<const float4*>(&As[kk][rt * 8]);
            float4 a1 = *reinterpret_cast<const float4*>(&As[kk][rt * 8 + 4]);
            float4 b = *reinterpret_cast<const float4*>(&Bs[kk][cc]);
            float a[8] = {a0.x, a0.y, a0.z, a0.w, a1.x, a1.y, a1.z, a1.w};
#pragma unroll
            for (int i2 = 0; i2 < 8; ++i2) {
                acc[i2][0] = fmaf(a[i2], b.x, acc[i2][0]);
                acc[i2][1] = fmaf(a[i2], b.y, acc[i2][1]);
                acc[i2][2] = fmaf(a[i2], b.z, acc[i2][2]);
                acc[i2][3] = fmaf(a[i2], b.w, acc[i2][3]);
            }
        }
        __syncthreads();
    }
    if (ct < 25) {
#pragma unroll
        for (int i2 = 0; i2 < 8; ++i2) {
            float* p = C2 + (size_t)(bm + rt * 8 + i2) * N2 + ct * 4;
            atomicAdd(p + 0, acc[i2][0]);
            atomicAdd(p + 1, acc[i2][1]);
            atomicAdd(p + 2, acc[i2][2]);
            atomicAdd(p + 3, acc[i2][3]);
        }
    }
}

// ---------------- r2 + MLP: one wave per batch row ----------------
__global__ __launch_bounds__(64) void k_r2mlp(const float* __restrict__ C2,
                                              const float* __restrict__ fc2b,
                                              const float* __restrict__ others,
                                              const float* __restrict__ m1w,
                                              const float* __restrict__ m1b,
                                              const float* __restrict__ m2w,
                                              const float* __restrict__ m2b,
                                              float* __restrict__ out) {
    const int b = blockIdx.x;
    const int t = threadIdx.x;
    float v1a, v2a, v1b = 0.f, v2b = 0.f;
    {
        float bb = fc2b[t];
        v1a = C2[(size_t)b * N2 + t] + bb;
        v2a = C2[(size_t)(b + BATCH) * N2 + t] + bb;
    }
    const bool sec = (t + 64) < N2;
    if (sec) {
        float bb = fc2b[t + 64];
        v1b = C2[(size_t)b * N2 + t + 64] + bb;
        v2b = C2[(size_t)(b + BATCH) * N2 + t + 64] + bb;
    }
    float s1 = v1a + v1b, s2 = v2a + v2b;
#pragma unroll
    for (int o = 32; o; o >>= 1) {
        s1 += __shfl_xor(s1, o, 64);
        s2 += __shfl_xor(s2, o, 64);
    }
    const float inv = 1.0f / (float)N2;
    float m1 = s1 * inv, m2 = s2 * inv;
    float c1a = v1a - m1, c2a = v2a - m2;
    float c1b = sec ? v1b - m1 : 0.f, c2b = sec ? v2b - m2 : 0.f;
    float num = c1a * c2a + c1b * c2b;
    float d1 = c1a * c1a + c1b * c1b;
    float d2 = c2a * c2a + c2b * c2b;
#pragma unroll
    for (int o = 32; o; o >>= 1) {
        num += __shfl_xor(num, o, 64);
        d1 += __shfl_xor(d1, o, 64);
        d2 += __shfl_xor(d2, o, 64);
    }
    if (t == 0) {
        float r = num / (sqrtf(d1) * sqrtf(d2));
        float r2 = r * r;
        float z[5] = {r2, others[b * 4 + 0], others[b * 4 + 1], others[b * 4 + 2], others[b * 4 + 3]};
        float h[4];
#pragma unroll
        for (int j = 0; j < 4; ++j) {
            float a = m1b[j];
#pragma unroll
            for (int i = 0; i < 5; ++i) a = fmaf(z[i], m1w[i * 4 + j], a);
            h[j] = fmaxf(a, 0.f);
        }
#pragma unroll
        for (int o = 0; o < 2; ++o) {
            float a = m2b[o];
#pragma unroll
            for (int j = 0; j < 4; ++j) a = fmaf(h[j], m2w[j * 2 + o], a);
            out[b * 2 + o] = a;
        }
    }
}

extern "C" void kernel_launch(void* const* d_in, const int* in_sizes, int n_in,
                              void* d_out, int out_size, void* d_ws, size_t ws_size,
                              hipStream_t stream) {
    const float* x1    = (const float*)d_in[0];
    const float* x2    = (const float*)d_in[1];
    const int*   edges = (const int*)d_in[2];
    const float* oth   = (const float*)d_in[3];
    const float* gw    = (const float*)d_in[4];
    const float* gb    = (const float*)d_in[5];
    const float* fc1w  = (const float*)d_in[6];
    const float* fc1b  = (const float*)d_in[7];
    const float* fc2w  = (const float*)d_in[8];
    const float* fc2b  = (const float*)d_in[9];
    const float* m1w   = (const float*)d_in[10];
    const float* m1b   = (const float*)d_in[11];
    const float* m2w   = (const float*)d_in[12];
    const float* m2b   = (const float*)d_in[13];

    float* ws   = (float*)d_ws;
    float* agg  = ws + OFF_AGG;
    float* C2   = ws + OFF_C2;
    int*   cur  = (int*)(ws + OFF_CUR);
    float* xi   = ws + OFF_XI;
    float* C1   = ws + OFF_C1;
    float* aggN = ws + OFF_AGGN;
    unsigned* bkt = (unsigned*)(ws + OFF_BKT);
    float* out = (float*)d_out;

    k_interleave<<<(NNODES / 4 + 255) / 256, 256, 0, stream>>>(x1, x2, xi);

    if (ws_size >= NEED_BYTES) {
        // C2 + cursors zeroed in one contiguous memset; aggN zeroed for atomic merge
        hipMemsetAsync(C2, 0, (size_t)(MR * N2 + 1024) * sizeof(float), stream);
        hipMemsetAsync(aggN, 0, (size_t)(2 * NNODES) * sizeof(float), stream);
        k_scatter<<<NEDGES / SCHUNK, 256, 0, stream>>>(edges, cur, bkt);
        k_accum<<<NBKT * 2, 256, 0, stream>>>(bkt, cur, xi, aggN);
        k_reshape<<<BATCH * (KPAD / 4) / 256, 256, 0, stream>>>(aggN, agg);
    } else {
        // fallback: round-0 atomic path (agg+C2 contiguous memset)
        hipMemsetAsync(agg, 0, (size_t)(MR * KPAD + MR * N2) * sizeof(float), stream);
        k_edges<<<NEDGES / 4 / 256, 256, 0, stream>>>(edges, xi, agg);
    }

    k_gemm1<<<dim3(16, 16), 512, 0, stream>>>(agg, fc1w, fc1b, gw, gb, C1);
    k_gemm2<<<dim3(32, 8), 256, 0, stream>>>(C1, fc2w, C2);
    k_r2mlp<<<1024, 64, 0, stream>>>(C2, fc2b, oth, m1w, m1b, m2w, m2b, out);
}

// Round 4
// 875.137 us; speedup vs baseline: 2.7847x; 1.2059x over previous
//
#include <hip/hip_runtime.h>

#define NG 978
#define BATCH 1024
#define MR 2048            // 2*BATCH stacked rows (enc1 rows 0..1023, enc2 1024..2047)
#define KPAD 1024          // padded K stride for agg (zero-padded cols 978..1023)
#define NEDGES 20480000
#define NNODES (BATCH * NG)   // 1001472 = 978 buckets * 1024 nodes
#define N1 2048            // fc1 out
#define N2 100             // fc2 out
#define NBKT 978
#define BCAP 24576         // bucket capacity: mean 20941 + ~25 sigma
#define SCHUNK 8192        // edges per scatter block (2500 blocks)

// ws layout in floats:
// [agg (MR*KPAD) | C2 (MR*N2) | CUR (1024) | xi (2*NNODES) | C1 (MR*N1) | aggN (2*NNODES) | BKT (NBKT*BCAP)]
#define OFF_AGG 0
#define OFF_C2  (OFF_AGG + MR * KPAD)          // 2,097,152
#define OFF_CUR (OFF_C2 + MR * N2)             // 2,301,952
#define OFF_XI  (OFF_CUR + 1024)               // 2,302,976
#define OFF_C1  (OFF_XI + 2 * NNODES)          // 4,305,920
#define OFF_AGGN (OFF_C1 + MR * N1)            // 8,500,224
#define OFF_BKT (OFF_AGGN + 2 * NNODES)        // 10,503,168
#define OFF_END (OFF_BKT + NBKT * BCAP)        // 34,538,496 floats = ~132 MB
#define NEED_BYTES ((size_t)OFF_END * 4)

// ---------------- interleave x1,x2 -> xi (float2 per node) ----------------
__global__ __launch_bounds__(256) void k_interleave(const float* __restrict__ x1,
                                                    const float* __restrict__ x2,
                                                    float* __restrict__ xi) {
    int i = blockIdx.x * 256 + threadIdx.x;   // float4 group index
    if (i >= NNODES / 4) return;
    float4 a = reinterpret_cast<const float4*>(x1)[i];
    float4 b = reinterpret_cast<const float4*>(x2)[i];
    float4 lo = make_float4(a.x, b.x, a.y, b.y);
    float4 hi = make_float4(a.z, b.z, a.w, b.w);
    reinterpret_cast<float4*>(xi)[2 * i + 0] = lo;
    reinterpret_cast<float4*>(xi)[2 * i + 1] = hi;
}

// ---------------- bin edges by dst bucket (dst>>10), packed (src<<10)|dstLow --------------
// Block-local counting sort in LDS so global bucket writes are COALESCED runs:
// histogram -> scan -> LDS re-scatter ordered by bucket -> linear write-out.
__global__ __launch_bounds__(256) void k_scatter(const int* __restrict__ edges,
                                                 int* __restrict__ cursor,
                                                 unsigned* __restrict__ bkt) {
    __shared__ int cnt[1024];               // per-bucket count
    __shared__ int loff[1024];              // exclusive local offset (consumed in phase 3)
    __shared__ int gbase[1024];             // b*BCAP + lbase[b] - loff0[b]
    __shared__ unsigned sdata[SCHUNK];      // packed words ordered by bucket (32 KB)
    __shared__ unsigned short sbid[SCHUNK]; // bucket id per slot (16 KB)
    __shared__ int wsum[4];

    const int t = threadIdx.x;
    const int lane = t & 63, wid = t >> 6;
    const int chunk = blockIdx.x * SCHUNK;
    const int4* d4 = reinterpret_cast<const int4*>(edges + NEDGES + chunk);
    const int4* s4 = reinterpret_cast<const int4*>(edges + chunk);

    for (int i = t; i < 1024; i += 256) cnt[i] = 0;
    __syncthreads();

    // phase 1: histogram
#pragma unroll
    for (int j = 0; j < SCHUNK / 1024; ++j) {   // 8
        int4 d = d4[t + j * 256];
        atomicAdd(&cnt[d.x >> 10], 1);
        atomicAdd(&cnt[d.y >> 10], 1);
        atomicAdd(&cnt[d.z >> 10], 1);
        atomicAdd(&cnt[d.w >> 10], 1);
    }
    __syncthreads();

    // phase 2: exclusive scan over 1024 buckets (4 per thread) + global reservation
    {
        int b0 = t * 4;
        int c0 = cnt[b0], c1 = cnt[b0 + 1], c2 = cnt[b0 + 2], c3 = cnt[b0 + 3];
        int s = c0 + c1 + c2 + c3;
        int x = s;
#pragma unroll
        for (int o = 1; o < 64; o <<= 1) {
            int y = __shfl_up(x, o, 64);
            if (lane >= o) x += y;
        }
        if (lane == 63) wsum[wid] = x;
        __syncthreads();
        int wpre = 0;
        for (int w = 0; w < wid; ++w) wpre += wsum[w];
        int e0 = wpre + x - s;   // exclusive prefix for bucket b0
        int l0 = e0, l1 = e0 + c0, l2 = l1 + c1, l3 = l2 + c2;
        loff[b0] = l0; loff[b0 + 1] = l1; loff[b0 + 2] = l2; loff[b0 + 3] = l3;
        int lb;
        lb = c0 ? atomicAdd(&cursor[b0], c0) : 0;
        gbase[b0] = b0 * BCAP + lb - l0;
        lb = c1 ? atomicAdd(&cursor[b0 + 1], c1) : 0;
        gbase[b0 + 1] = (b0 + 1) * BCAP + lb - l1;
        lb = c2 ? atomicAdd(&cursor[b0 + 2], c2) : 0;
        gbase[b0 + 2] = (b0 + 2) * BCAP + lb - l2;
        lb = c3 ? atomicAdd(&cursor[b0 + 3], c3) : 0;
        gbase[b0 + 3] = (b0 + 3) * BCAP + lb - l3;
    }
    __syncthreads();

    // phase 3: re-read edges (L2-hot), scatter into LDS ordered by bucket
#pragma unroll
    for (int j = 0; j < SCHUNK / 1024; ++j) {
        int4 d = d4[t + j * 256];
        int4 s = s4[t + j * 256];
        int dd[4] = {d.x, d.y, d.z, d.w};
        int ss[4] = {s.x, s.y, s.z, s.w};
#pragma unroll
        for (int u = 0; u < 4; ++u) {
            int b = dd[u] >> 10;
            int pos = atomicAdd(&loff[b], 1);
            sdata[pos] = ((unsigned)ss[u] << 10) | (unsigned)(dd[u] & 1023);
            sbid[pos] = (unsigned short)b;
        }
    }
    __syncthreads();

    // phase 5: linear write-out -> coalesced runs per bucket
#pragma unroll 4
    for (int e = t; e < SCHUNK; e += 256) {
        int bid = sbid[e];
        int idx = gbase[bid] + e;
        unsigned slot = (unsigned)(idx - bid * BCAP);
        if (slot < BCAP)   // statistically impossible overflow guard
            bkt[idx] = sdata[e];
    }
}

// ---------------- accumulate: four blocks per bucket (edge-range split), LDS accumulation,
// coalesced atomic merge into zeroed aggN ----------------
__global__ __launch_bounds__(256) void k_accum(const unsigned* __restrict__ bkt,
                                               const int* __restrict__ cursor,
                                               const float* __restrict__ xi,
                                               float* __restrict__ aggN) {
    __shared__ float accX[1024];
    __shared__ float accY[1024];
    const int b = blockIdx.x >> 2;
    const int q = blockIdx.x & 3;
    const int t = threadIdx.x;
    for (int i = t; i < 1024; i += 256) { accX[i] = 0.f; accY[i] = 0.f; }
    __syncthreads();
    const int n = cursor[b];
    const int lo = (n * q) >> 2;
    const int hi = (n * (q + 1)) >> 2;
    const unsigned* bp = bkt + (size_t)b * BCAP;
    const float2* xi2 = reinterpret_cast<const float2*>(xi);
    int i = lo + t;
    for (; i + 256 < hi; i += 512) {
        unsigned p0 = bp[i];
        unsigned p1 = bp[i + 256];
        float2 v0 = xi2[p0 >> 10];
        float2 v1 = xi2[p1 >> 10];
        atomicAdd(&accX[p0 & 1023], v0.x);
        atomicAdd(&accY[p0 & 1023], v0.y);
        atomicAdd(&accX[p1 & 1023], v1.x);
        atomicAdd(&accY[p1 & 1023], v1.y);
    }
    if (i < hi) {
        unsigned p0 = bp[i];
        float2 v0 = xi2[p0 >> 10];
        atomicAdd(&accX[p0 & 1023], v0.x);
        atomicAdd(&accY[p0 & 1023], v0.y);
    }
    __syncthreads();
    float* o = aggN + ((size_t)b << 11);
    for (int j = t; j < 1024; j += 256) {
        atomicAdd(o + 2 * j + 0, accX[j]);
        atomicAdd(o + 2 * j + 1, accY[j]);
    }
}

// ---------------- reshape node-indexed aggN -> two padded planes ----------------
__global__ __launch_bounds__(256) void k_reshape(const float* __restrict__ aggN,
                                                 float* __restrict__ agg) {
    int idx = blockIdx.x * 256 + threadIdx.x;   // BATCH * KPAD/4 = 262144
    int row = idx >> 8;
    int c4 = (idx & 255) << 2;
    const float2* a2 = reinterpret_cast<const float2*>(aggN);
    float4 vx = make_float4(0.f, 0.f, 0.f, 0.f);
    float4 vy = make_float4(0.f, 0.f, 0.f, 0.f);
    float* px = &vx.x;
    float* py = &vy.x;
#pragma unroll
    for (int u = 0; u < 4; ++u) {
        int col = c4 + u;
        if (col < NG) {
            float2 v = a2[(size_t)row * NG + col];
            px[u] = v.x;
            py[u] = v.y;
        }
    }
    *reinterpret_cast<float4*>(&agg[(size_t)row * KPAD + c4]) = vx;
    *reinterpret_cast<float4*>(&agg[(size_t)(BATCH + row) * KPAD + c4]) = vy;
}

// ---------------- fallback edge kernel (round-0 path, used if ws too small) ----------------
__global__ __launch_bounds__(256) void k_edges(const int* __restrict__ edges,
                                               const float* __restrict__ xi,
                                               float* __restrict__ agg) {
    int t = blockIdx.x * 256 + threadIdx.x;
    int e = t * 4;
    const int4 s4 = *reinterpret_cast<const int4*>(edges + e);
    const int4 d4 = *reinterpret_cast<const int4*>(edges + NEDGES + e);
    int ss[4] = {s4.x, s4.y, s4.z, s4.w};
    int dd[4] = {d4.x, d4.y, d4.z, d4.w};
#pragma unroll
    for (int j = 0; j < 4; ++j) {
        int s = ss[j];
        int d = dd[j];
        float2 xv = *reinterpret_cast<const float2*>(xi + 2 * (size_t)s);
        int row = d / NG;
        int col = d - row * NG;
        float* p = agg + (size_t)row * KPAD + col;
        atomicAdd(p, xv.x);
        atomicAdd(p + (size_t)BATCH * KPAD, xv.y);
    }
}

// ---------------- GEMM1: C1 = relu( relu(agg*gw+gb) @ W + bias ) ----------------
// M=2048, K=978 (stride 1024, zero-padded), N=2048. 128x128 tile, BK=16,
// 512 threads (8 waves -> 2/SIMD), 4x8 acc/thread.
__global__ __launch_bounds__(512) void k_gemm1(const float* __restrict__ agg,
                                               const float* __restrict__ W,    // (978,2048)
                                               const float* __restrict__ bias, // (2048)
                                               const float* __restrict__ gwp,
                                               const float* __restrict__ gbp,
                                               float* __restrict__ C1) {
    __shared__ float As[16][132];
    __shared__ float Bs[16][132];
    const int tid = threadIdx.x;
    const int bm = blockIdx.y * 128;
    const int bn = blockIdx.x * 128;
    const float gw = gwp[0], gb = gbp[0];
    const int rt = tid >> 4;   // 0..31 -> rows rt*4..+3
    const int ct = tid & 15;   // 0..15 -> cols ct*8..+7

    float acc[4][8] = {};

    for (int k0 = 0; k0 < NG; k0 += 16) {
        {   // stage A: 128 rows x 16 k = 512 float4, 1 per thread; affine+relu here
            int r = tid >> 2;
            int k4 = (tid & 3) << 2;
            float4 v = *reinterpret_cast<const float4*>(agg + (size_t)(bm + r) * KPAD + k0 + k4);
            v.x = fmaxf(v.x * gw + gb, 0.f);
            v.y = fmaxf(v.y * gw + gb, 0.f);
            v.z = fmaxf(v.z * gw + gb, 0.f);
            v.w = fmaxf(v.w * gw + gb, 0.f);
            As[k4 + 0][r] = v.x;
            As[k4 + 1][r] = v.y;
            As[k4 + 2][r] = v.z;
            As[k4 + 3][r] = v.w;
        }
        {   // stage B: 16 rows x 128 cols = 512 float4, 1 per thread (rows >= 978 zeroed)
            int row = tid >> 5;
            int c4 = (tid & 31) << 2;
            int gk = k0 + row;
            float4 v = make_float4(0.f, 0.f, 0.f, 0.f);
            if (gk < NG) v = *reinterpret_cast<const float4*>(W + (size_t)gk * N1 + bn + c4);
            int pc = c4 + ((c4 >> 6) << 2);
            *reinterpret_cast<float4*>(&Bs[row][pc]) = v;
        }
        __syncthreads();
#pragma unroll
        for (int kk = 0; kk < 16; ++kk) {
            float4 a0 = *reinterpret_cast<const float4*>(&As[kk][rt * 4]);
            int cb = ct * 8;
            int pc = cb + ((cb >> 6) << 2);
            float4 b0 = *reinterpret_cast<const float4*>(&Bs[kk][pc]);
            float4 b1 = *reinterpret_cast<const float4*>(&Bs[kk][pc + 4]);
            float a[4] = {a0.x, a0.y, a0.z, a0.w};
            float b[8] = {b0.x, b0.y, b0.z, b0.w, b1.x, b1.y, b1.z, b1.w};
#pragma unroll
            for (int i2 = 0; i2 < 4; ++i2)
#pragma unroll
                for (int j2 = 0; j2 < 8; ++j2)
                    acc[i2][j2] = fmaf(a[i2], b[j2], acc[i2][j2]);
        }
        __syncthreads();
    }
    const int cbase = bn + ct * 8;
    float4 bb0 = *reinterpret_cast<const float4*>(&bias[cbase]);
    float4 bb1 = *reinterpret_cast<const float4*>(&bias[cbase + 4]);
    float bz[8] = {bb0.x, bb0.y, bb0.z, bb0.w, bb1.x, bb1.y, bb1.z, bb1.w};
#pragma unroll
    for (int i2 = 0; i2 < 4; ++i2) {
        int row = bm + rt * 4 + i2;
        float4 o0, o1;
        o0.x = fmaxf(acc[i2][0] + bz[0], 0.f);
        o0.y = fmaxf(acc[i2][1] + bz[1], 0.f);
        o0.z = fmaxf(acc[i2][2] + bz[2], 0.f);
        o0.w = fmaxf(acc[i2][3] + bz[3], 0.f);
        o1.x = fmaxf(acc[i2][4] + bz[4], 0.f);
        o1.y = fmaxf(acc[i2][5] + bz[5], 0.f);
        o1.z = fmaxf(acc[i2][6] + bz[6], 0.f);
        o1.w = fmaxf(acc[i2][7] + bz[7], 0.f);
        *reinterpret_cast<float4*>(&C1[(size_t)row * N1 + cbase]) = o0;
        *reinterpret_cast<float4*>(&C1[(size_t)row * N1 + cbase + 4]) = o1;
    }
}

// ---------------- GEMM2: C2 += C1 @ fc2_w  (split-K, atomic accumulate) ----------------
__global__ __launch_bounds__(256) void k_gemm2(const float* __restrict__ C1,
                                               const float* __restrict__ W,  // (2048,100)
                                               float* __restrict__ C2) {
    __shared__ float As[16][68];
    __shared__ float Bs[16][132];
    const int tid = threadIdx.x;
    const int bm = blockIdx.x * 64;
    const int k_base = blockIdx.y * 256;
    const int rt = tid >> 5;
    const int ct = tid & 31;
    float acc[8][4] = {};

    for (int k0 = k_base; k0 < k_base + 256; k0 += 16) {
        {
            int r = tid >> 2;
            int k4 = (tid & 3) << 2;
            float4 v = *reinterpret_cast<const float4*>(C1 + (size_t)(bm + r) * N1 + k0 + k4);
            As[k4 + 0][r] = v.x;
            As[k4 + 1][r] = v.y;
            As[k4 + 2][r] = v.z;
            As[k4 + 3][r] = v.w;
        }
#pragma unroll
        for (int h = 0; h < 2; ++h) {
            int i = tid + h * 256;
            if (i < 400) {
                int kk = i / 25;
                int c4 = (i % 25) * 4;
                *reinterpret_cast<float4*>(&Bs[kk][c4]) =
                    *reinterpret_cast<const float4*>(W + (size_t)(k0 + kk) * N2 + c4);
            }
        }
        __syncthreads();
        int cc = (ct < 25) ? ct * 4 : 100;
#pragma unroll
        for (int kk = 0; kk < 16; ++kk) {
            float4 a0 = *reinterpret_cast<const float4*>(&As[kk][rt * 8]);
            float4 a1 = *reinterpret_cast<const float4*>(&As[kk][rt * 8 + 4]);
            float4 b = *reinterpret_cast<const float4*>(&Bs[kk][cc]);
            float a[8] = {a0.x, a0.y, a0.z, a0.w, a1.x, a1.y, a1.z, a1.w};
#pragma unroll
            for (int i2 = 0; i2 < 8; ++i2) {
                acc[i2][0] = fmaf(a[i2], b.x, acc[i2][0]);
                acc[i2][1] = fmaf(a[i2], b.y, acc[i2][1]);
                acc[i2][2] = fmaf(a[i2], b.z, acc[i2][2]);
                acc[i2][3] = fmaf(a[i2], b.w, acc[i2][3]);
            }
        }
        __syncthreads();
    }
    if (ct < 25) {
#pragma unroll
        for (int i2 = 0; i2 < 8; ++i2) {
            float* p = C2 + (size_t)(bm + rt * 8 + i2) * N2 + ct * 4;
            atomicAdd(p + 0, acc[i2][0]);
            atomicAdd(p + 1, acc[i2][1]);
            atomicAdd(p + 2, acc[i2][2]);
            atomicAdd(p + 3, acc[i2][3]);
        }
    }
}

// ---------------- r2 + MLP: one wave per batch row ----------------
__global__ __launch_bounds__(64) void k_r2mlp(const float* __restrict__ C2,
                                              const float* __restrict__ fc2b,
                                              const float* __restrict__ others,
                                              const float* __restrict__ m1w,
                                              const float* __restrict__ m1b,
                                              const float* __restrict__ m2w,
                                              const float* __restrict__ m2b,
                                              float* __restrict__ out) {
    const int b = blockIdx.x;
    const int t = threadIdx.x;
    float v1a, v2a, v1b = 0.f, v2b = 0.f;
    {
        float bb = fc2b[t];
        v1a = C2[(size_t)b * N2 + t] + bb;
        v2a = C2[(size_t)(b + BATCH) * N2 + t] + bb;
    }
    const bool sec = (t + 64) < N2;
    if (sec) {
        float bb = fc2b[t + 64];
        v1b = C2[(size_t)b * N2 + t + 64] + bb;
        v2b = C2[(size_t)(b + BATCH) * N2 + t + 64] + bb;
    }
    float s1 = v1a + v1b, s2 = v2a + v2b;
#pragma unroll
    for (int o = 32; o; o >>= 1) {
        s1 += __shfl_xor(s1, o, 64);
        s2 += __shfl_xor(s2, o, 64);
    }
    const float inv = 1.0f / (float)N2;
    float m1 = s1 * inv, m2 = s2 * inv;
    float c1a = v1a - m1, c2a = v2a - m2;
    float c1b = sec ? v1b - m1 : 0.f, c2b = sec ? v2b - m2 : 0.f;
    float num = c1a * c2a + c1b * c2b;
    float d1 = c1a * c1a + c1b * c1b;
    float d2 = c2a * c2a + c2b * c2b;
#pragma unroll
    for (int o = 32; o; o >>= 1) {
        num += __shfl_xor(num, o, 64);
        d1 += __shfl_xor(d1, o, 64);
        d2 += __shfl_xor(d2, o, 64);
    }
    if (t == 0) {
        float r = num / (sqrtf(d1) * sqrtf(d2));
        float r2 = r * r;
        float z[5] = {r2, others[b * 4 + 0], others[b * 4 + 1], others[b * 4 + 2], others[b * 4 + 3]};
        float h[4];
#pragma unroll
        for (int j = 0; j < 4; ++j) {
            float a = m1b[j];
#pragma unroll
            for (int i = 0; i < 5; ++i) a = fmaf(z[i], m1w[i * 4 + j], a);
            h[j] = fmaxf(a, 0.f);
        }
#pragma unroll
        for (int o = 0; o < 2; ++o) {
            float a = m2b[o];
#pragma unroll
            for (int j = 0; j < 4; ++j) a = fmaf(h[j], m2w[j * 2 + o], a);
            out[b * 2 + o] = a;
        }
    }
}

extern "C" void kernel_launch(void* const* d_in, const int* in_sizes, int n_in,
                              void* d_out, int out_size, void* d_ws, size_t ws_size,
                              hipStream_t stream) {
    const float* x1    = (const float*)d_in[0];
    const float* x2    = (const float*)d_in[1];
    const int*   edges = (const int*)d_in[2];
    const float* oth   = (const float*)d_in[3];
    const float* gw    = (const float*)d_in[4];
    const float* gb    = (const float*)d_in[5];
    const float* fc1w  = (const float*)d_in[6];
    const float* fc1b  = (const float*)d_in[7];
    const float* fc2w  = (const float*)d_in[8];
    const float* fc2b  = (const float*)d_in[9];
    const float* m1w   = (const float*)d_in[10];
    const float* m1b   = (const float*)d_in[11];
    const float* m2w   = (const float*)d_in[12];
    const float* m2b   = (const float*)d_in[13];

    float* ws   = (float*)d_ws;
    float* agg  = ws + OFF_AGG;
    float* C2   = ws + OFF_C2;
    int*   cur  = (int*)(ws + OFF_CUR);
    float* xi   = ws + OFF_XI;
    float* C1   = ws + OFF_C1;
    float* aggN = ws + OFF_AGGN;
    unsigned* bkt = (unsigned*)(ws + OFF_BKT);
    float* out = (float*)d_out;

    k_interleave<<<(NNODES / 4 + 255) / 256, 256, 0, stream>>>(x1, x2, xi);

    if (ws_size >= NEED_BYTES) {
        // C2 + cursors zeroed in one contiguous memset; aggN zeroed for atomic merge
        hipMemsetAsync(C2, 0, (size_t)(MR * N2 + 1024) * sizeof(float), stream);
        hipMemsetAsync(aggN, 0, (size_t)(2 * NNODES) * sizeof(float), stream);
        k_scatter<<<NEDGES / SCHUNK, 256, 0, stream>>>(edges, cur, bkt);
        k_accum<<<NBKT * 4, 256, 0, stream>>>(bkt, cur, xi, aggN);
        k_reshape<<<BATCH * (KPAD / 4) / 256, 256, 0, stream>>>(aggN, agg);
    } else {
        // fallback: round-0 atomic path (agg+C2 contiguous memset)
        hipMemsetAsync(agg, 0, (size_t)(MR * KPAD + MR * N2) * sizeof(float), stream);
        k_edges<<<NEDGES / 4 / 256, 256, 0, stream>>>(edges, xi, agg);
    }

    k_gemm1<<<dim3(16, 16), 512, 0, stream>>>(agg, fc1w, fc1b, gw, gb, C1);
    k_gemm2<<<dim3(32, 8), 256, 0, stream>>>(C1, fc2w, C2);
    k_r2mlp<<<1024, 64, 0, stream>>>(C2, fc2b, oth, m1w, m1b, m2w, m2b, out);
}

// Round 5
// 764.990 us; speedup vs baseline: 3.1856x; 1.1440x over previous
//
#include <hip/hip_runtime.h>

#define NG 978
#define BATCH 1024
#define MR 2048            // 2*BATCH stacked rows (enc1 rows 0..1023, enc2 1024..2047)
#define KPAD 1024          // padded K stride for agg (zero-padded cols 978..1023)
#define NEDGES 20480000
#define NNODES (BATCH * NG)   // 1001472 = 978 buckets * 1024 nodes
#define N1 2048            // fc1 out
#define N2 100             // fc2 out
#define NBKT 978
#define BCAP 24576         // bucket capacity: mean 20941 + ~25 sigma
#define SCHUNK 8192        // edges per scatter block (2500 blocks)
#define PLANE (2 * NNODES) // one accum output plane (float), 2,002,944

// ws layout in floats:
// [agg (MR*KPAD) | C2 (MR*N2) | CUR (1024) | xi (2*NNODES) | C1 (MR*N1) | aggN (unused now) | BKT (NBKT*BCAP)]
// accum planes (2 x PLANE = 4,005,888 floats) overlay the C1 region (4,194,304 floats):
// accum writes planes -> reshape consumes them -> gemm1 overwrites C1. Ordering-safe.
#define OFF_AGG 0
#define OFF_C2  (OFF_AGG + MR * KPAD)          // 2,097,152
#define OFF_CUR (OFF_C2 + MR * N2)             // 2,301,952
#define OFF_XI  (OFF_CUR + 1024)               // 2,302,976
#define OFF_C1  (OFF_XI + 2 * NNODES)          // 4,305,920
#define OFF_AGGN (OFF_C1 + MR * N1)            // 8,500,224 (unused, kept for layout stability)
#define OFF_BKT (OFF_AGGN + 2 * NNODES)        // 10,503,168
#define OFF_END (OFF_BKT + NBKT * BCAP)        // 34,538,496 floats = ~132 MB
#define NEED_BYTES ((size_t)OFF_END * 4)

// ---------------- interleave x1,x2 -> xi (float2 per node) ----------------
__global__ __launch_bounds__(256) void k_interleave(const float* __restrict__ x1,
                                                    const float* __restrict__ x2,
                                                    float* __restrict__ xi) {
    int i = blockIdx.x * 256 + threadIdx.x;   // float4 group index
    if (i >= NNODES / 4) return;
    float4 a = reinterpret_cast<const float4*>(x1)[i];
    float4 b = reinterpret_cast<const float4*>(x2)[i];
    float4 lo = make_float4(a.x, b.x, a.y, b.y);
    float4 hi = make_float4(a.z, b.z, a.w, b.w);
    reinterpret_cast<float4*>(xi)[2 * i + 0] = lo;
    reinterpret_cast<float4*>(xi)[2 * i + 1] = hi;
}

// ---------------- bin edges by dst bucket (dst>>10), packed (src<<10)|dstLow --------------
// Block-local counting sort in LDS; bucket id at write-out recovered by binary search
// over the saved prefix array (no sbid array -> 48 KB LDS -> 3 blocks/CU).
// Edges are cached in registers across phases (single global read of the edge list).
__global__ __launch_bounds__(512) void k_scatter(const int* __restrict__ edges,
                                                 int* __restrict__ cursor,
                                                 unsigned* __restrict__ bkt) {
    __shared__ int cnt[1024];          // per-bucket count
    __shared__ int l0[1024];           // exclusive prefix (pristine snapshot for search)
    __shared__ int loff[1024];         // running cursor for LDS re-scatter
    __shared__ int gbase[1024];        // global base - l0 (bucket-relative)
    __shared__ unsigned sdata[SCHUNK]; // packed words ordered by bucket (32 KB)
    __shared__ int wsum[8];

    const int t = threadIdx.x;         // 0..511
    const int lane = t & 63, wid = t >> 6;
    const int chunk = blockIdx.x * SCHUNK;
    const int4* d4 = reinterpret_cast<const int4*>(edges + NEDGES + chunk);
    const int4* s4 = reinterpret_cast<const int4*>(edges + chunk);

    for (int i = t; i < 1024; i += 512) cnt[i] = 0;

    // single global read of this block's edges; keep in registers across phases
    int4 dreg[4], sreg[4];
#pragma unroll
    for (int j = 0; j < 4; ++j) {
        dreg[j] = d4[t + j * 512];
        sreg[j] = s4[t + j * 512];
    }
    __syncthreads();

    // phase 1: histogram
#pragma unroll
    for (int j = 0; j < 4; ++j) {
        atomicAdd(&cnt[dreg[j].x >> 10], 1);
        atomicAdd(&cnt[dreg[j].y >> 10], 1);
        atomicAdd(&cnt[dreg[j].z >> 10], 1);
        atomicAdd(&cnt[dreg[j].w >> 10], 1);
    }
    __syncthreads();

    // phase 2: exclusive scan over 1024 buckets (2 per thread) + global reservation
    {
        int b0 = t * 2;
        int c0 = cnt[b0], c1 = cnt[b0 + 1];
        int s = c0 + c1;
        int x = s;
#pragma unroll
        for (int o = 1; o < 64; o <<= 1) {
            int y = __shfl_up(x, o, 64);
            if (lane >= o) x += y;
        }
        if (lane == 63) wsum[wid] = x;
        __syncthreads();
        int wpre = 0;
        for (int w = 0; w < wid; ++w) wpre += wsum[w];
        int e0 = wpre + x - s;          // exclusive prefix for bucket b0
        l0[b0] = e0;       l0[b0 + 1] = e0 + c0;
        loff[b0] = e0;     loff[b0 + 1] = e0 + c0;
        int lb;
        lb = c0 ? atomicAdd(&cursor[b0], c0) : 0;
        gbase[b0] = lb - e0;
        lb = c1 ? atomicAdd(&cursor[b0 + 1], c1) : 0;
        gbase[b0 + 1] = lb - (e0 + c0);
    }
    __syncthreads();

    // phase 3: scatter packed words into LDS ordered by bucket (from registers)
#pragma unroll
    for (int j = 0; j < 4; ++j) {
        int dd[4] = {dreg[j].x, dreg[j].y, dreg[j].z, dreg[j].w};
        int ss[4] = {sreg[j].x, sreg[j].y, sreg[j].z, sreg[j].w};
#pragma unroll
        for (int u = 0; u < 4; ++u) {
            int b = dd[u] >> 10;
            int pos = atomicAdd(&loff[b], 1);
            sdata[pos] = ((unsigned)ss[u] << 10) | (unsigned)(dd[u] & 1023);
        }
    }
    __syncthreads();

    // phase 4: linear write-out; bucket id via binary search over l0 (10 steps)
#pragma unroll 4
    for (int e = t; e < SCHUNK; e += 512) {
        unsigned w = sdata[e];
        int b = 0;
#pragma unroll
        for (int step = 512; step >= 1; step >>= 1) {
            int nb = b + step;
            if (nb < 1024 && l0[nb] <= e) b = nb;
        }
        unsigned slot = (unsigned)(gbase[b] + e);
        if (slot < BCAP)   // statistically impossible overflow guard
            bkt[(size_t)b * BCAP + slot] = w;
    }
}

// ---------------- accumulate: two blocks per bucket (edge-range split), LDS accumulation,
// plain coalesced plane writes (no global atomics; planes summed in k_reshape) ----------------
__global__ __launch_bounds__(256) void k_accum(const unsigned* __restrict__ bkt,
                                               const int* __restrict__ cursor,
                                               const float* __restrict__ xi,
                                               float* __restrict__ planes) {
    __shared__ float accX[1024];
    __shared__ float accY[1024];
    const int b = blockIdx.x >> 1;
    const int h = blockIdx.x & 1;
    const int t = threadIdx.x;
    for (int i = t; i < 1024; i += 256) { accX[i] = 0.f; accY[i] = 0.f; }
    __syncthreads();
    const int n = cursor[b];
    const int lo = h ? (n >> 1) : 0;
    const int hi = h ? n : (n >> 1);
    const unsigned* bp = bkt + (size_t)b * BCAP;
    const float2* xi2 = reinterpret_cast<const float2*>(xi);
    int i = lo + t;
    for (; i + 256 < hi; i += 512) {
        unsigned p0 = bp[i];
        unsigned p1 = bp[i + 256];
        float2 v0 = xi2[p0 >> 10];
        float2 v1 = xi2[p1 >> 10];
        atomicAdd(&accX[p0 & 1023], v0.x);
        atomicAdd(&accY[p0 & 1023], v0.y);
        atomicAdd(&accX[p1 & 1023], v1.x);
        atomicAdd(&accY[p1 & 1023], v1.y);
    }
    if (i < hi) {
        unsigned p0 = bp[i];
        float2 v0 = xi2[p0 >> 10];
        atomicAdd(&accX[p0 & 1023], v0.x);
        atomicAdd(&accY[p0 & 1023], v0.y);
    }
    __syncthreads();
    float2* o = reinterpret_cast<float2*>(planes + (size_t)h * PLANE) + ((size_t)b << 10);
    for (int j = t; j < 1024; j += 256) o[j] = make_float2(accX[j], accY[j]);
}

// ---------------- reshape: sum 2 node-indexed planes -> two padded row-major planes -------
__global__ __launch_bounds__(256) void k_reshape(const float* __restrict__ planes,
                                                 float* __restrict__ agg) {
    int idx = blockIdx.x * 256 + threadIdx.x;   // BATCH * KPAD/4 = 262144
    int row = idx >> 8;
    int c4 = (idx & 255) << 2;
    const float2* p0 = reinterpret_cast<const float2*>(planes);
    const float2* p1 = reinterpret_cast<const float2*>(planes + PLANE);
    float4 vx = make_float4(0.f, 0.f, 0.f, 0.f);
    float4 vy = make_float4(0.f, 0.f, 0.f, 0.f);
    float* px = &vx.x;
    float* py = &vy.x;
#pragma unroll
    for (int u = 0; u < 4; ++u) {
        int col = c4 + u;
        if (col < NG) {
            size_t ni = (size_t)row * NG + col;
            float2 a = p0[ni];
            float2 b = p1[ni];
            px[u] = a.x + b.x;
            py[u] = a.y + b.y;
        }
    }
    *reinterpret_cast<float4*>(&agg[(size_t)row * KPAD + c4]) = vx;
    *reinterpret_cast<float4*>(&agg[(size_t)(BATCH + row) * KPAD + c4]) = vy;
}

// ---------------- fallback edge kernel (round-0 path, used if ws too small) ----------------
__global__ __launch_bounds__(256) void k_edges(const int* __restrict__ edges,
                                               const float* __restrict__ xi,
                                               float* __restrict__ agg) {
    int t = blockIdx.x * 256 + threadIdx.x;
    int e = t * 4;
    const int4 s4 = *reinterpret_cast<const int4*>(edges + e);
    const int4 d4 = *reinterpret_cast<const int4*>(edges + NEDGES + e);
    int ss[4] = {s4.x, s4.y, s4.z, s4.w};
    int dd[4] = {d4.x, d4.y, d4.z, d4.w};
#pragma unroll
    for (int j = 0; j < 4; ++j) {
        int s = ss[j];
        int d = dd[j];
        float2 xv = *reinterpret_cast<const float2*>(xi + 2 * (size_t)s);
        int row = d / NG;
        int col = d - row * NG;
        float* p = agg + (size_t)row * KPAD + col;
        atomicAdd(p, xv.x);
        atomicAdd(p + (size_t)BATCH * KPAD, xv.y);
    }
}

// ---------------- GEMM1: C1 = relu( relu(agg*gw+gb) @ W + bias ) ----------------
// M=2048, K=978 (stride 1024, zero-padded), N=2048. 128x128 tile, BK=16,
// 512 threads (8 waves -> 2/SIMD), 4x8 acc/thread.
__global__ __launch_bounds__(512) void k_gemm1(const float* __restrict__ agg,
                                               const float* __restrict__ W,    // (978,2048)
                                               const float* __restrict__ bias, // (2048)
                                               const float* __restrict__ gwp,
                                               const float* __restrict__ gbp,
                                               float* __restrict__ C1) {
    __shared__ float As[16][132];
    __shared__ float Bs[16][132];
    const int tid = threadIdx.x;
    const int bm = blockIdx.y * 128;
    const int bn = blockIdx.x * 128;
    const float gw = gwp[0], gb = gbp[0];
    const int rt = tid >> 4;   // 0..31 -> rows rt*4..+3
    const int ct = tid & 15;   // 0..15 -> cols ct*8..+7

    float acc[4][8] = {};

    for (int k0 = 0; k0 < NG; k0 += 16) {
        {   // stage A: 128 rows x 16 k = 512 float4, 1 per thread; affine+relu here
            int r = tid >> 2;
            int k4 = (tid & 3) << 2;
            float4 v = *reinterpret_cast<const float4*>(agg + (size_t)(bm + r) * KPAD + k0 + k4);
            v.x = fmaxf(v.x * gw + gb, 0.f);
            v.y = fmaxf(v.y * gw + gb, 0.f);
            v.z = fmaxf(v.z * gw + gb, 0.f);
            v.w = fmaxf(v.w * gw + gb, 0.f);
            As[k4 + 0][r] = v.x;
            As[k4 + 1][r] = v.y;
            As[k4 + 2][r] = v.z;
            As[k4 + 3][r] = v.w;
        }
        {   // stage B: 16 rows x 128 cols = 512 float4, 1 per thread (rows >= 978 zeroed)
            int row = tid >> 5;
            int c4 = (tid & 31) << 2;
            int gk = k0 + row;
            float4 v = make_float4(0.f, 0.f, 0.f, 0.f);
            if (gk < NG) v = *reinterpret_cast<const float4*>(W + (size_t)gk * N1 + bn + c4);
            int pc = c4 + ((c4 >> 6) << 2);
            *reinterpret_cast<float4*>(&Bs[row][pc]) = v;
        }
        __syncthreads();
#pragma unroll
        for (int kk = 0; kk < 16; ++kk) {
            float4 a0 = *reinterpret_cast<const float4*>(&As[kk][rt * 4]);
            int cb = ct * 8;
            int pc = cb + ((cb >> 6) << 2);
            float4 b0 = *reinterpret_cast<const float4*>(&Bs[kk][pc]);
            float4 b1 = *reinterpret_cast<const float4*>(&Bs[kk][pc + 4]);
            float a[4] = {a0.x, a0.y, a0.z, a0.w};
            float b[8] = {b0.x, b0.y, b0.z, b0.w, b1.x, b1.y, b1.z, b1.w};
#pragma unroll
            for (int i2 = 0; i2 < 4; ++i2)
#pragma unroll
                for (int j2 = 0; j2 < 8; ++j2)
                    acc[i2][j2] = fmaf(a[i2], b[j2], acc[i2][j2]);
        }
        __syncthreads();
    }
    const int cbase = bn + ct * 8;
    float4 bb0 = *reinterpret_cast<const float4*>(&bias[cbase]);
    float4 bb1 = *reinterpret_cast<const float4*>(&bias[cbase + 4]);
    float bz[8] = {bb0.x, bb0.y, bb0.z, bb0.w, bb1.x, bb1.y, bb1.z, bb1.w};
#pragma unroll
    for (int i2 = 0; i2 < 4; ++i2) {
        int row = bm + rt * 4 + i2;
        float4 o0, o1;
        o0.x = fmaxf(acc[i2][0] + bz[0], 0.f);
        o0.y = fmaxf(acc[i2][1] + bz[1], 0.f);
        o0.z = fmaxf(acc[i2][2] + bz[2], 0.f);
        o0.w = fmaxf(acc[i2][3] + bz[3], 0.f);
        o1.x = fmaxf(acc[i2][4] + bz[4], 0.f);
        o1.y = fmaxf(acc[i2][5] + bz[5], 0.f);
        o1.z = fmaxf(acc[i2][6] + bz[6], 0.f);
        o1.w = fmaxf(acc[i2][7] + bz[7], 0.f);
        *reinterpret_cast<float4*>(&C1[(size_t)row * N1 + cbase]) = o0;
        *reinterpret_cast<float4*>(&C1[(size_t)row * N1 + cbase + 4]) = o1;
    }
}

// ---------------- GEMM2: C2 += C1 @ fc2_w  (split-K, atomic accumulate) ----------------
__global__ __launch_bounds__(256) void k_gemm2(const float* __restrict__ C1,
                                               const float* __restrict__ W,  // (2048,100)
                                               float* __restrict__ C2) {
    __shared__ float As[16][68];
    __shared__ float Bs[16][132];
    const int tid = threadIdx.x;
    const int bm = blockIdx.x * 64;
    const int k_base = blockIdx.y * 256;
    const int rt = tid >> 5;
    const int ct = tid & 31;
    float acc[8][4] = {};

    for (int k0 = k_base; k0 < k_base + 256; k0 += 16) {
        {
            int r = tid >> 2;
            int k4 = (tid & 3) << 2;
            float4 v = *reinterpret_cast<const float4*>(C1 + (size_t)(bm + r) * N1 + k0 + k4);
            As[k4 + 0][r] = v.x;
            As[k4 + 1][r] = v.y;
            As[k4 + 2][r] = v.z;
            As[k4 + 3][r] = v.w;
        }
#pragma unroll
        for (int h = 0; h < 2; ++h) {
            int i = tid + h * 256;
            if (i < 400) {
                int kk = i / 25;
                int c4 = (i % 25) * 4;
                *reinterpret_cast<float4*>(&Bs[kk][c4]) =
                    *reinterpret_cast<const float4*>(W + (size_t)(k0 + kk) * N2 + c4);
            }
        }
        __syncthreads();
        int cc = (ct < 25) ? ct * 4 : 100;
#pragma unroll
        for (int kk = 0; kk < 16; ++kk) {
            float4 a0 = *reinterpret_cast<const float4*>(&As[kk][rt * 8]);
            float4 a1 = *reinterpret_cast<const float4*>(&As[kk][rt * 8 + 4]);
            float4 b = *reinterpret_cast<const float4*>(&Bs[kk][cc]);
            float a[8] = {a0.x, a0.y, a0.z, a0.w, a1.x, a1.y, a1.z, a1.w};
#pragma unroll
            for (int i2 = 0; i2 < 8; ++i2) {
                acc[i2][0] = fmaf(a[i2], b.x, acc[i2][0]);
                acc[i2][1] = fmaf(a[i2], b.y, acc[i2][1]);
                acc[i2][2] = fmaf(a[i2], b.z, acc[i2][2]);
                acc[i2][3] = fmaf(a[i2], b.w, acc[i2][3]);
            }
        }
        __syncthreads();
    }
    if (ct < 25) {
#pragma unroll
        for (int i2 = 0; i2 < 8; ++i2) {
            float* p = C2 + (size_t)(bm + rt * 8 + i2) * N2 + ct * 4;
            atomicAdd(p + 0, acc[i2][0]);
            atomicAdd(p + 1, acc[i2][1]);
            atomicAdd(p + 2, acc[i2][2]);
            atomicAdd(p + 3, acc[i2][3]);
        }
    }
}

// ---------------- r2 + MLP: one wave per batch row ----------------
__global__ __launch_bounds__(64) void k_r2mlp(const float* __restrict__ C2,
                                              const float* __restrict__ fc2b,
                                              const float* __restrict__ others,
                                              const float* __restrict__ m1w,
                                              const float* __restrict__ m1b,
                                              const float* __restrict__ m2w,
                                              const float* __restrict__ m2b,
                                              float* __restrict__ out) {
    const int b = blockIdx.x;
    const int t = threadIdx.x;
    float v1a, v2a, v1b = 0.f, v2b = 0.f;
    {
        float bb = fc2b[t];
        v1a = C2[(size_t)b * N2 + t] + bb;
        v2a = C2[(size_t)(b + BATCH) * N2 + t] + bb;
    }
    const bool sec = (t + 64) < N2;
    if (sec) {
        float bb = fc2b[t + 64];
        v1b = C2[(size_t)b * N2 + t + 64] + bb;
        v2b = C2[(size_t)(b + BATCH) * N2 + t + 64] + bb;
    }
    float s1 = v1a + v1b, s2 = v2a + v2b;
#pragma unroll
    for (int o = 32; o; o >>= 1) {
        s1 += __shfl_xor(s1, o, 64);
        s2 += __shfl_xor(s2, o, 64);
    }
    const float inv = 1.0f / (float)N2;
    float m1 = s1 * inv, m2 = s2 * inv;
    float c1a = v1a - m1, c2a = v2a - m2;
    float c1b = sec ? v1b - m1 : 0.f, c2b = sec ? v2b - m2 : 0.f;
    float num = c1a * c2a + c1b * c2b;
    float d1 = c1a * c1a + c1b * c1b;
    float d2 = c2a * c2a + c2b * c2b;
#pragma unroll
    for (int o = 32; o; o >>= 1) {
        num += __shfl_xor(num, o, 64);
        d1 += __shfl_xor(d1, o, 64);
        d2 += __shfl_xor(d2, o, 64);
    }
    if (t == 0) {
        float r = num / (sqrtf(d1) * sqrtf(d2));
        float r2 = r * r;
        float z[5] = {r2, others[b * 4 + 0], others[b * 4 + 1], others[b * 4 + 2], others[b * 4 + 3]};
        float h[4];
#pragma unroll
        for (int j = 0; j < 4; ++j) {
            float a = m1b[j];
#pragma unroll
            for (int i = 0; i < 5; ++i) a = fmaf(z[i], m1w[i * 4 + j], a);
            h[j] = fmaxf(a, 0.f);
        }
#pragma unroll
        for (int o = 0; o < 2; ++o) {
            float a = m2b[o];
#pragma unroll
            for (int j = 0; j < 4; ++j) a = fmaf(h[j], m2w[j * 2 + o], a);
            out[b * 2 + o] = a;
        }
    }
}

extern "C" void kernel_launch(void* const* d_in, const int* in_sizes, int n_in,
                              void* d_out, int out_size, void* d_ws, size_t ws_size,
                              hipStream_t stream) {
    const float* x1    = (const float*)d_in[0];
    const float* x2    = (const float*)d_in[1];
    const int*   edges = (const int*)d_in[2];
    const float* oth   = (const float*)d_in[3];
    const float* gw    = (const float*)d_in[4];
    const float* gb    = (const float*)d_in[5];
    const float* fc1w  = (const float*)d_in[6];
    const float* fc1b  = (const float*)d_in[7];
    const float* fc2w  = (const float*)d_in[8];
    const float* fc2b  = (const float*)d_in[9];
    const float* m1w   = (const float*)d_in[10];
    const float* m1b   = (const float*)d_in[11];
    const float* m2w   = (const float*)d_in[12];
    const float* m2b   = (const float*)d_in[13];

    float* ws   = (float*)d_ws;
    float* agg  = ws + OFF_AGG;
    float* C2   = ws + OFF_C2;
    int*   cur  = (int*)(ws + OFF_CUR);
    float* xi   = ws + OFF_XI;
    float* C1   = ws + OFF_C1;
    float* planes = C1;                 // accum planes overlay C1 (dead until gemm1)
    unsigned* bkt = (unsigned*)(ws + OFF_BKT);
    float* out = (float*)d_out;

    k_interleave<<<(NNODES / 4 + 255) / 256, 256, 0, stream>>>(x1, x2, xi);

    if (ws_size >= NEED_BYTES) {
        // C2 + cursors zeroed in one contiguous memset
        hipMemsetAsync(C2, 0, (size_t)(MR * N2 + 1024) * sizeof(float), stream);
        k_scatter<<<NEDGES / SCHUNK, 512, 0, stream>>>(edges, cur, bkt);
        k_accum<<<NBKT * 2, 256, 0, stream>>>(bkt, cur, xi, planes);
        k_reshape<<<BATCH * (KPAD / 4) / 256, 256, 0, stream>>>(planes, agg);
    } else {
        // fallback: round-0 atomic path (agg+C2 contiguous memset)
        hipMemsetAsync(agg, 0, (size_t)(MR * KPAD + MR * N2) * sizeof(float), stream);
        k_edges<<<NEDGES / 4 / 256, 256, 0, stream>>>(edges, xi, agg);
    }

    k_gemm1<<<dim3(16, 16), 512, 0, stream>>>(agg, fc1w, fc1b, gw, gb, C1);
    k_gemm2<<<dim3(32, 8), 256, 0, stream>>>(C1, fc2w, C2);
    k_r2mlp<<<1024, 64, 0, stream>>>(C2, fc2b, oth, m1w, m1b, m2w, m2b, out);
}